// Round 1
// baseline (3311.405 us; speedup 1.0000x reference)
//
#include <hip/hip_runtime.h>

#define DIM 128

// ---------------------------------------------------------------------------
// K0: v0[k] = sum_j outW0[j,k]*regW[j] ; v1[k] = sum_j outW1[j,k]*regW[128+j]
//     c = regb + dot(outb0, regW[:128]) + dot(outb1, regW[128:])
// ---------------------------------------------------------------------------
__global__ void precompute_v_kernel(const float* __restrict__ outW0,
                                    const float* __restrict__ outW1,
                                    const float* __restrict__ outb0,
                                    const float* __restrict__ outb1,
                                    const float* __restrict__ regW,
                                    const float* __restrict__ regb,
                                    float* __restrict__ vbuf) {
    int t = threadIdx.x;  // 256 threads, 1 block
    if (t < DIM) {
        float s = 0.f;
        #pragma unroll 8
        for (int j = 0; j < DIM; ++j) s = fmaf(outW0[j * DIM + t], regW[j], s);
        vbuf[t] = s;
    } else {
        int k = t - DIM;
        float s = 0.f;
        #pragma unroll 8
        for (int j = 0; j < DIM; ++j) s = fmaf(outW1[j * DIM + k], regW[DIM + j], s);
        vbuf[t] = s;
    }
    if (t == 0) {
        float c = regb[0];
        for (int j = 0; j < DIM; ++j) c += outb0[j] * regW[j] + outb1[j] * regW[DIM + j];
        vbuf[2 * DIM] = c;
    }
}

// ---------------------------------------------------------------------------
// Edge-parallel scatter-mean accumulate: one wave per edge, float2 per lane.
// ei layout: (2,E) int32 -> src = ei[0:E], dst = ei[E:2E]
// ---------------------------------------------------------------------------
__global__ void scatter_kernel(const float* __restrict__ xsrc,
                               const int* __restrict__ ei,
                               int nedges,
                               float* __restrict__ agg,
                               float* __restrict__ cnt) {
    const int* __restrict__ src = ei;
    const int* __restrict__ dst = ei + nedges;
    int gtid = blockIdx.x * blockDim.x + threadIdx.x;
    int wid = gtid >> 6;
    int lane = threadIdx.x & 63;
    int nw = (gridDim.x * blockDim.x) >> 6;
    for (int e = wid; e < nedges; e += nw) {
        int s = src[e];
        int d = dst[e];
        const float2 v = *reinterpret_cast<const float2*>(xsrc + (size_t)s * DIM + lane * 2);
        float* ap = agg + (size_t)d * DIM + lane * 2;
        atomicAdd(ap, v.x);
        atomicAdd(ap + 1, v.y);
        if (lane == 0) atomicAdd(cnt + d, 1.0f);
    }
}

// ---------------------------------------------------------------------------
// Fused SAGE hop GEMM:  h[i,:] = relu( (agg[i]/max(cnt,1)) @ Wl^T + x_dst[i] @ Wr^T + bl )
// As one K=256 GEMM with A = [mean, xdst], B = [Wl | Wr] (row j, 256 wide).
// MODE 0: store h -> H.   MODE 1: out[i]  = c + dot(h, v).   MODE 2: out[i] += dot(h, v).
// BM=128, BN=128, BK=32; 256 threads; 8x8 micro-tile.
// ---------------------------------------------------------------------------
template <int MODE>
__launch_bounds__(256, 2)
__global__ void sage_gemm_kernel(const float* __restrict__ agg,
                                 const float* __restrict__ cnt,
                                 const float* __restrict__ xdst,
                                 const float* __restrict__ Wl,
                                 const float* __restrict__ Wr,
                                 const float* __restrict__ bl,
                                 float* __restrict__ H,
                                 const float* __restrict__ v,
                                 const float* __restrict__ cptr,
                                 float* __restrict__ out,
                                 int nrows) {
    __shared__ float As[32][DIM + 4];   // [k][m] transposed A tile
    __shared__ float Bs[32][DIM + 4];   // [k][n] transposed B tile
    __shared__ float sScale[DIM];

    const int tid = threadIdx.x;
    const int tx = tid & 15;       // col group: cols tx*8 .. +8
    const int ty = tid >> 4;       // row group: rows ty*8 .. +8
    const int row0 = blockIdx.x * DIM;

    if (tid < DIM) {
        int row = row0 + tid;
        float c = (row < nrows) ? cnt[row] : 1.0f;
        sScale[tid] = 1.0f / fmaxf(c, 1.0f);
    }
    __syncthreads();

    float acc[8][8];
    #pragma unroll
    for (int i = 0; i < 8; ++i)
        #pragma unroll
        for (int j = 0; j < 8; ++j) acc[i][j] = 0.f;

    for (int kt = 0; kt < 8; ++kt) {
        const bool first = (kt < 4);                 // uniform per tile
        const float* __restrict__ Asrc = first ? agg : xdst;
        const float* __restrict__ W = first ? Wl : Wr;
        const int kb = (kt & 3) * 32;

        // stage A: 128 rows x 32 k  (each thread: 4 float4 loads)
        #pragma unroll
        for (int p = 0; p < 4; ++p) {
            int rl = p * 32 + (tid >> 3);
            int kk = (tid & 7) * 4;
            int row = row0 + rl;
            float4 val = make_float4(0.f, 0.f, 0.f, 0.f);
            if (row < nrows) {
                val = *reinterpret_cast<const float4*>(Asrc + (size_t)row * DIM + kb + kk);
                if (first) {
                    float s = sScale[rl];
                    val.x *= s; val.y *= s; val.z *= s; val.w *= s;
                }
            }
            As[kk + 0][rl] = val.x;
            As[kk + 1][rl] = val.y;
            As[kk + 2][rl] = val.z;
            As[kk + 3][rl] = val.w;
        }
        // stage B: Bs[k][j] = W[j][kb+k]
        #pragma unroll
        for (int p = 0; p < 4; ++p) {
            int j = p * 32 + (tid >> 3);
            int kk = (tid & 7) * 4;
            float4 w = *reinterpret_cast<const float4*>(W + j * DIM + kb + kk);
            Bs[kk + 0][j] = w.x;
            Bs[kk + 1][j] = w.y;
            Bs[kk + 2][j] = w.z;
            Bs[kk + 3][j] = w.w;
        }
        __syncthreads();

        #pragma unroll
        for (int k = 0; k < 32; ++k) {
            float4 a0 = *reinterpret_cast<const float4*>(&As[k][ty * 8]);
            float4 a1 = *reinterpret_cast<const float4*>(&As[k][ty * 8 + 4]);
            float4 b0 = *reinterpret_cast<const float4*>(&Bs[k][tx * 8]);
            float4 b1 = *reinterpret_cast<const float4*>(&Bs[k][tx * 8 + 4]);
            float av[8] = {a0.x, a0.y, a0.z, a0.w, a1.x, a1.y, a1.z, a1.w};
            float bv[8] = {b0.x, b0.y, b0.z, b0.w, b1.x, b1.y, b1.z, b1.w};
            #pragma unroll
            for (int i = 0; i < 8; ++i)
                #pragma unroll
                for (int j = 0; j < 8; ++j)
                    acc[i][j] = fmaf(av[i], bv[j], acc[i][j]);
        }
        __syncthreads();
    }

    // bias for this thread's 8 columns
    float blv[8];
    {
        float4 b0 = *reinterpret_cast<const float4*>(bl + tx * 8);
        float4 b1 = *reinterpret_cast<const float4*>(bl + tx * 8 + 4);
        blv[0] = b0.x; blv[1] = b0.y; blv[2] = b0.z; blv[3] = b0.w;
        blv[4] = b1.x; blv[5] = b1.y; blv[6] = b1.z; blv[7] = b1.w;
    }

    if (MODE == 0) {
        #pragma unroll
        for (int i = 0; i < 8; ++i) {
            int row = row0 + ty * 8 + i;
            if (row < nrows) {
                float4 o0, o1;
                o0.x = fmaxf(acc[i][0] + blv[0], 0.f);
                o0.y = fmaxf(acc[i][1] + blv[1], 0.f);
                o0.z = fmaxf(acc[i][2] + blv[2], 0.f);
                o0.w = fmaxf(acc[i][3] + blv[3], 0.f);
                o1.x = fmaxf(acc[i][4] + blv[4], 0.f);
                o1.y = fmaxf(acc[i][5] + blv[5], 0.f);
                o1.z = fmaxf(acc[i][6] + blv[6], 0.f);
                o1.w = fmaxf(acc[i][7] + blv[7], 0.f);
                *reinterpret_cast<float4*>(H + (size_t)row * DIM + tx * 8) = o0;
                *reinterpret_cast<float4*>(H + (size_t)row * DIM + tx * 8 + 4) = o1;
            }
        }
    } else {
        float vv[8];
        {
            float4 v0 = *reinterpret_cast<const float4*>(v + tx * 8);
            float4 v1 = *reinterpret_cast<const float4*>(v + tx * 8 + 4);
            vv[0] = v0.x; vv[1] = v0.y; vv[2] = v0.z; vv[3] = v0.w;
            vv[4] = v1.x; vv[5] = v1.y; vv[6] = v1.z; vv[7] = v1.w;
        }
        float cbase = (MODE == 1) ? cptr[0] : 0.f;
        #pragma unroll
        for (int i = 0; i < 8; ++i) {
            float p = 0.f;
            #pragma unroll
            for (int j = 0; j < 8; ++j)
                p = fmaf(fmaxf(acc[i][j] + blv[j], 0.f), vv[j], p);
            // reduce across the 16 tx lanes (lane bits 0..3)
            p += __shfl_xor(p, 1);
            p += __shfl_xor(p, 2);
            p += __shfl_xor(p, 4);
            p += __shfl_xor(p, 8);
            int row = row0 + ty * 8 + i;
            if (tx == 0 && row < nrows) {
                if (MODE == 1) out[row] = cbase + p;
                else out[row] += p;
            }
        }
    }
}

// ---------------------------------------------------------------------------
extern "C" void kernel_launch(void* const* d_in, const int* in_sizes, int n_in,
                              void* d_out, int out_size, void* d_ws, size_t ws_size,
                              hipStream_t stream) {
    const float* x_user = (const float*)d_in[0];
    const float* x_item = (const float*)d_in[1];
    const int* ei_m0_h0 = (const int*)d_in[2];
    const int* ei_m0_h1 = (const int*)d_in[3];
    const int* ei_m1_h0 = (const int*)d_in[4];
    const int* ei_m1_h1 = (const int*)d_in[5];
    const float* Wl00 = (const float*)d_in[6];
    const float* Wr00 = (const float*)d_in[7];
    const float* Wl01 = (const float*)d_in[8];
    const float* Wr01 = (const float*)d_in[9];
    const float* Wl10 = (const float*)d_in[10];
    const float* Wr10 = (const float*)d_in[11];
    const float* Wl11 = (const float*)d_in[12];
    const float* Wr11 = (const float*)d_in[13];
    const float* outW0 = (const float*)d_in[14];
    const float* outW1 = (const float*)d_in[15];
    const float* bl00 = (const float*)d_in[16];
    const float* bl01 = (const float*)d_in[17];
    const float* bl10 = (const float*)d_in[18];
    const float* bl11 = (const float*)d_in[19];
    const float* outb0 = (const float*)d_in[20];
    const float* outb1 = (const float*)d_in[21];
    const float* regW = (const float*)d_in[22];
    const float* regb = (const float*)d_in[23];

    const int N = in_sizes[0] / DIM;
    const int E = in_sizes[2] / 2;
    float* out = (float*)d_out;

    // workspace layout (floats): agg[N*DIM] | cnt[N] | hi[N*DIM] | vbuf[257]
    float* ws = (float*)d_ws;
    float* agg = ws;
    float* cnt = agg + (size_t)N * DIM;
    float* hi = cnt + N;
    float* vbuf = hi + (size_t)N * DIM;

    precompute_v_kernel<<<1, 256, 0, stream>>>(outW0, outW1, outb0, outb1, regW, regb, vbuf);

    const int gemmBlocks = (N + DIM - 1) / DIM;
    const int scatBlocks = 4096;
    const size_t zbytes = ((size_t)N * DIM + N) * sizeof(float);

    // ---- metapath 0 ----
    hipMemsetAsync(agg, 0, zbytes, stream);
    scatter_kernel<<<scatBlocks, 256, 0, stream>>>(x_user, ei_m0_h0, E, agg, cnt);
    sage_gemm_kernel<0><<<gemmBlocks, 256, 0, stream>>>(agg, cnt, x_item, Wl00, Wr00, bl00,
                                                        hi, nullptr, nullptr, nullptr, N);
    hipMemsetAsync(agg, 0, zbytes, stream);
    scatter_kernel<<<scatBlocks, 256, 0, stream>>>(hi, ei_m0_h1, E, agg, cnt);
    sage_gemm_kernel<1><<<gemmBlocks, 256, 0, stream>>>(agg, cnt, x_user, Wl01, Wr01, bl01,
                                                        nullptr, vbuf, vbuf + 2 * DIM, out, N);

    // ---- metapath 1 ----
    hipMemsetAsync(agg, 0, zbytes, stream);
    scatter_kernel<<<scatBlocks, 256, 0, stream>>>(x_user, ei_m1_h0, E, agg, cnt);
    sage_gemm_kernel<0><<<gemmBlocks, 256, 0, stream>>>(agg, cnt, x_item, Wl10, Wr10, bl10,
                                                        hi, nullptr, nullptr, nullptr, N);
    hipMemsetAsync(agg, 0, zbytes, stream);
    scatter_kernel<<<scatBlocks, 256, 0, stream>>>(hi, ei_m1_h1, E, agg, cnt);
    sage_gemm_kernel<2><<<gemmBlocks, 256, 0, stream>>>(agg, cnt, x_user, Wl11, Wr11, bl11,
                                                        nullptr, vbuf + DIM, vbuf + 2 * DIM, out, N);
}

// Round 2
// 1851.846 us; speedup vs baseline: 1.7882x; 1.7882x over previous
//
#include <hip/hip_runtime.h>

#define DIM 128

// ---------------------------------------------------------------------------
// K0: v0[k] = sum_j outW0[j,k]*regW[j] ; v1[k] = sum_j outW1[j,k]*regW[128+j]
//     c = regb + dot(outb0, regW[:128]) + dot(outb1, regW[128:])
// ---------------------------------------------------------------------------
__global__ void precompute_v_kernel(const float* __restrict__ outW0,
                                    const float* __restrict__ outW1,
                                    const float* __restrict__ outb0,
                                    const float* __restrict__ outb1,
                                    const float* __restrict__ regW,
                                    const float* __restrict__ regb,
                                    float* __restrict__ vbuf) {
    int t = threadIdx.x;  // 256 threads, 1 block
    if (t < DIM) {
        float s = 0.f;
        #pragma unroll 8
        for (int j = 0; j < DIM; ++j) s = fmaf(outW0[j * DIM + t], regW[j], s);
        vbuf[t] = s;
    } else {
        int k = t - DIM;
        float s = 0.f;
        #pragma unroll 8
        for (int j = 0; j < DIM; ++j) s = fmaf(outW1[j * DIM + k], regW[DIM + j], s);
        vbuf[t] = s;
    }
    if (t == 0) {
        float c = regb[0];
        for (int j = 0; j < DIM; ++j) c += outb0[j] * regW[j] + outb1[j] * regW[DIM + j];
        vbuf[2 * DIM] = c;
    }
}

// ---------------------------------------------------------------------------
// CSR build: histogram, exclusive scan, fill
// ---------------------------------------------------------------------------
__global__ void hist_kernel(const int* __restrict__ ei, int nedges, int* __restrict__ deg) {
    const int* __restrict__ dst = ei + nedges;
    int i = blockIdx.x * blockDim.x + threadIdx.x;
    int stride = gridDim.x * blockDim.x;
    for (int e = i; e < nedges; e += stride) atomicAdd(&deg[dst[e]], 1);
}

__global__ void exscan_kernel(const int* __restrict__ deg, int* __restrict__ rowptr, int n) {
    __shared__ int part[1024];
    int t = threadIdx.x;
    int chunk = (n + 1023) / 1024;
    int beg = t * chunk;
    int end = min(beg + chunk, n);
    int s = 0;
    for (int i = beg; i < end; ++i) s += deg[i];
    part[t] = s;
    __syncthreads();
    // inclusive Hillis-Steele scan over 1024 partials
    for (int off = 1; off < 1024; off <<= 1) {
        int v = (t >= off) ? part[t - off] : 0;
        __syncthreads();
        part[t] += v;
        __syncthreads();
    }
    int base = (t == 0) ? 0 : part[t - 1];
    for (int i = beg; i < end; ++i) {
        rowptr[i] = base;
        base += deg[i];
    }
    if (t == 0) rowptr[n] = part[1023];
}

__global__ void fill_kernel(const int* __restrict__ ei, int nedges,
                            int* __restrict__ cursor, int* __restrict__ eidx) {
    const int* __restrict__ src = ei;
    const int* __restrict__ dst = ei + nedges;
    int i = blockIdx.x * blockDim.x + threadIdx.x;
    int stride = gridDim.x * blockDim.x;
    for (int e = i; e < nedges; e += stride) {
        int s = src[e];
        int d = dst[e];
        int pos = atomicAdd(&cursor[d], 1);
        eidx[pos] = s;
    }
}

// ---------------------------------------------------------------------------
// Gather-side mean aggregation: one wave per dst row, float2 per lane.
// mean[r,:] = (1/max(deg,1)) * sum_{j in row r} xsrc[eidx[j], :]
// ---------------------------------------------------------------------------
__global__ void aggregate_kernel(const float* __restrict__ xsrc,
                                 const int* __restrict__ rowptr,
                                 const int* __restrict__ eidx,
                                 float* __restrict__ mean, int n) {
    int wid = (blockIdx.x * blockDim.x + threadIdx.x) >> 6;
    int lane = threadIdx.x & 63;
    int nw = (gridDim.x * blockDim.x) >> 6;
    for (int r = wid; r < n; r += nw) {
        int beg = rowptr[r];
        int end = rowptr[r + 1];
        float ax = 0.f, ay = 0.f;
        for (int j = beg; j < end; ++j) {
            int s = eidx[j];   // wave-uniform -> scalar load
            float2 v = *reinterpret_cast<const float2*>(xsrc + (size_t)s * DIM + lane * 2);
            ax += v.x;
            ay += v.y;
        }
        float sc = 1.0f / fmaxf((float)(end - beg), 1.0f);
        float2 o;
        o.x = ax * sc;
        o.y = ay * sc;
        *reinterpret_cast<float2*>(mean + (size_t)r * DIM + lane * 2) = o;
    }
}

// ---------------------------------------------------------------------------
// Fused SAGE hop GEMM:  h[i,:] = relu( mean[i] @ Wl^T + x_dst[i] @ Wr^T + bl )
// One K=256 GEMM with A = [mean, xdst], B = [Wl | Wr].
// MODE 0: store h -> H.   MODE 1: out[i]  = c + dot(h, v).   MODE 2: out[i] += dot(h, v).
// BM=128, BN=128, BK=32; 256 threads; 8x8 micro-tile.
// ---------------------------------------------------------------------------
template <int MODE>
__launch_bounds__(256, 2)
__global__ void sage_gemm_kernel(const float* __restrict__ mean,
                                 const float* __restrict__ xdst,
                                 const float* __restrict__ Wl,
                                 const float* __restrict__ Wr,
                                 const float* __restrict__ bl,
                                 float* __restrict__ H,
                                 const float* __restrict__ v,
                                 const float* __restrict__ cptr,
                                 float* __restrict__ out,
                                 int nrows) {
    __shared__ float As[32][DIM + 4];   // [k][m] transposed A tile
    __shared__ float Bs[32][DIM + 4];   // [k][n] transposed B tile

    const int tid = threadIdx.x;
    const int tx = tid & 15;       // col group: cols tx*8 .. +8
    const int ty = tid >> 4;       // row group: rows ty*8 .. +8
    const int row0 = blockIdx.x * DIM;

    float acc[8][8];
    #pragma unroll
    for (int i = 0; i < 8; ++i)
        #pragma unroll
        for (int j = 0; j < 8; ++j) acc[i][j] = 0.f;

    for (int kt = 0; kt < 8; ++kt) {
        const bool first = (kt < 4);                 // uniform per tile
        const float* __restrict__ Asrc = first ? mean : xdst;
        const float* __restrict__ W = first ? Wl : Wr;
        const int kb = (kt & 3) * 32;

        // stage A: 128 rows x 32 k  (each thread: 4 float4 loads)
        #pragma unroll
        for (int p = 0; p < 4; ++p) {
            int rl = p * 32 + (tid >> 3);
            int kk = (tid & 7) * 4;
            int row = row0 + rl;
            float4 val = make_float4(0.f, 0.f, 0.f, 0.f);
            if (row < nrows) {
                val = *reinterpret_cast<const float4*>(Asrc + (size_t)row * DIM + kb + kk);
            }
            As[kk + 0][rl] = val.x;
            As[kk + 1][rl] = val.y;
            As[kk + 2][rl] = val.z;
            As[kk + 3][rl] = val.w;
        }
        // stage B: Bs[k][j] = W[j][kb+k]
        #pragma unroll
        for (int p = 0; p < 4; ++p) {
            int j = p * 32 + (tid >> 3);
            int kk = (tid & 7) * 4;
            float4 w = *reinterpret_cast<const float4*>(W + j * DIM + kb + kk);
            Bs[kk + 0][j] = w.x;
            Bs[kk + 1][j] = w.y;
            Bs[kk + 2][j] = w.z;
            Bs[kk + 3][j] = w.w;
        }
        __syncthreads();

        #pragma unroll
        for (int k = 0; k < 32; ++k) {
            float4 a0 = *reinterpret_cast<const float4*>(&As[k][ty * 8]);
            float4 a1 = *reinterpret_cast<const float4*>(&As[k][ty * 8 + 4]);
            float4 b0 = *reinterpret_cast<const float4*>(&Bs[k][tx * 8]);
            float4 b1 = *reinterpret_cast<const float4*>(&Bs[k][tx * 8 + 4]);
            float av[8] = {a0.x, a0.y, a0.z, a0.w, a1.x, a1.y, a1.z, a1.w};
            float bv[8] = {b0.x, b0.y, b0.z, b0.w, b1.x, b1.y, b1.z, b1.w};
            #pragma unroll
            for (int i = 0; i < 8; ++i)
                #pragma unroll
                for (int j = 0; j < 8; ++j)
                    acc[i][j] = fmaf(av[i], bv[j], acc[i][j]);
        }
        __syncthreads();
    }

    // bias for this thread's 8 columns
    float blv[8];
    {
        float4 b0 = *reinterpret_cast<const float4*>(bl + tx * 8);
        float4 b1 = *reinterpret_cast<const float4*>(bl + tx * 8 + 4);
        blv[0] = b0.x; blv[1] = b0.y; blv[2] = b0.z; blv[3] = b0.w;
        blv[4] = b1.x; blv[5] = b1.y; blv[6] = b1.z; blv[7] = b1.w;
    }

    if (MODE == 0) {
        #pragma unroll
        for (int i = 0; i < 8; ++i) {
            int row = row0 + ty * 8 + i;
            if (row < nrows) {
                float4 o0, o1;
                o0.x = fmaxf(acc[i][0] + blv[0], 0.f);
                o0.y = fmaxf(acc[i][1] + blv[1], 0.f);
                o0.z = fmaxf(acc[i][2] + blv[2], 0.f);
                o0.w = fmaxf(acc[i][3] + blv[3], 0.f);
                o1.x = fmaxf(acc[i][4] + blv[4], 0.f);
                o1.y = fmaxf(acc[i][5] + blv[5], 0.f);
                o1.z = fmaxf(acc[i][6] + blv[6], 0.f);
                o1.w = fmaxf(acc[i][7] + blv[7], 0.f);
                *reinterpret_cast<float4*>(H + (size_t)row * DIM + tx * 8) = o0;
                *reinterpret_cast<float4*>(H + (size_t)row * DIM + tx * 8 + 4) = o1;
            }
        }
    } else {
        float vv[8];
        {
            float4 v0 = *reinterpret_cast<const float4*>(v + tx * 8);
            float4 v1 = *reinterpret_cast<const float4*>(v + tx * 8 + 4);
            vv[0] = v0.x; vv[1] = v0.y; vv[2] = v0.z; vv[3] = v0.w;
            vv[4] = v1.x; vv[5] = v1.y; vv[6] = v1.z; vv[7] = v1.w;
        }
        float cbase = (MODE == 1) ? cptr[0] : 0.f;
        #pragma unroll
        for (int i = 0; i < 8; ++i) {
            float p = 0.f;
            #pragma unroll
            for (int j = 0; j < 8; ++j)
                p = fmaf(fmaxf(acc[i][j] + blv[j], 0.f), vv[j], p);
            // reduce across the 16 tx lanes (lane bits 0..3)
            p += __shfl_xor(p, 1);
            p += __shfl_xor(p, 2);
            p += __shfl_xor(p, 4);
            p += __shfl_xor(p, 8);
            int row = row0 + ty * 8 + i;
            if (tx == 0 && row < nrows) {
                if (MODE == 1) out[row] = cbase + p;
                else out[row] += p;
            }
        }
    }
}

// ---------------------------------------------------------------------------
extern "C" void kernel_launch(void* const* d_in, const int* in_sizes, int n_in,
                              void* d_out, int out_size, void* d_ws, size_t ws_size,
                              hipStream_t stream) {
    const float* x_user = (const float*)d_in[0];
    const float* x_item = (const float*)d_in[1];
    const int* ei_m0_h0 = (const int*)d_in[2];
    const int* ei_m0_h1 = (const int*)d_in[3];
    const int* ei_m1_h0 = (const int*)d_in[4];
    const int* ei_m1_h1 = (const int*)d_in[5];
    const float* Wl00 = (const float*)d_in[6];
    const float* Wr00 = (const float*)d_in[7];
    const float* Wl01 = (const float*)d_in[8];
    const float* Wr01 = (const float*)d_in[9];
    const float* Wl10 = (const float*)d_in[10];
    const float* Wr10 = (const float*)d_in[11];
    const float* Wl11 = (const float*)d_in[12];
    const float* Wr11 = (const float*)d_in[13];
    const float* outW0 = (const float*)d_in[14];
    const float* outW1 = (const float*)d_in[15];
    const float* bl00 = (const float*)d_in[16];
    const float* bl01 = (const float*)d_in[17];
    const float* bl10 = (const float*)d_in[18];
    const float* bl11 = (const float*)d_in[19];
    const float* outb0 = (const float*)d_in[20];
    const float* outb1 = (const float*)d_in[21];
    const float* regW = (const float*)d_in[22];
    const float* regb = (const float*)d_in[23];

    const int N = in_sizes[0] / DIM;
    const int E = in_sizes[2] / 2;
    float* out = (float*)d_out;

    // workspace layout: mean[N*DIM] f32 | hi[N*DIM] f32 | vbuf[2*DIM+1] f32 |
    //                   deg[N] i32 | rowptr[N+1] i32 | cursor[N] i32 | eidx[E] i32
    float* ws = (float*)d_ws;
    float* mean = ws;
    float* hi = mean + (size_t)N * DIM;
    float* vbuf = hi + (size_t)N * DIM;
    int* deg = (int*)(vbuf + 2 * DIM + 1);
    int* rowptr = deg + N;
    int* cursor = rowptr + N + 1;
    int* eidx = cursor + N;

    precompute_v_kernel<<<1, 256, 0, stream>>>(outW0, outW1, outb0, outb1, regW, regb, vbuf);

    const int gemmBlocks = (N + DIM - 1) / DIM;
    const int edgeBlocks = 1024;
    const int aggBlocks = 2048;

    struct Hop {
        const int* ei;
        const float* xsrc;
        const float* xdst;
        const float *Wl, *Wr, *bl;
        int mode;            // 0: ->hi, 1: ->out (=), 2: ->out (+=)
        const float* v;
    };
    const Hop hops[4] = {
        {ei_m0_h0, x_user, x_item, Wl00, Wr00, bl00, 0, nullptr},
        {ei_m0_h1, hi,     x_user, Wl01, Wr01, bl01, 1, vbuf},
        {ei_m1_h0, x_user, x_item, Wl10, Wr10, bl10, 0, nullptr},
        {ei_m1_h1, hi,     x_user, Wl11, Wr11, bl11, 2, vbuf + DIM},
    };

    for (int h = 0; h < 4; ++h) {
        const Hop& hp = hops[h];
        // CSR build
        hipMemsetAsync(deg, 0, (size_t)N * sizeof(int), stream);
        hist_kernel<<<edgeBlocks, 256, 0, stream>>>(hp.ei, E, deg);
        exscan_kernel<<<1, 1024, 0, stream>>>(deg, rowptr, N);
        hipMemcpyAsync(cursor, rowptr, (size_t)N * sizeof(int), hipMemcpyDeviceToDevice, stream);
        fill_kernel<<<edgeBlocks, 256, 0, stream>>>(hp.ei, E, cursor, eidx);
        // gather-side mean
        aggregate_kernel<<<aggBlocks, 256, 0, stream>>>(hp.xsrc, rowptr, eidx, mean, N);
        // fused GEMM
        if (hp.mode == 0)
            sage_gemm_kernel<0><<<gemmBlocks, 256, 0, stream>>>(mean, hp.xdst, hp.Wl, hp.Wr, hp.bl,
                                                                hi, nullptr, nullptr, nullptr, N);
        else if (hp.mode == 1)
            sage_gemm_kernel<1><<<gemmBlocks, 256, 0, stream>>>(mean, hp.xdst, hp.Wl, hp.Wr, hp.bl,
                                                                nullptr, hp.v, vbuf + 2 * DIM, out, N);
        else
            sage_gemm_kernel<2><<<gemmBlocks, 256, 0, stream>>>(mean, hp.xdst, hp.Wl, hp.Wr, hp.bl,
                                                                nullptr, hp.v, vbuf + 2 * DIM, out, N);
    }
}

// Round 3
// 1220.902 us; speedup vs baseline: 2.7123x; 1.5168x over previous
//
#include <hip/hip_runtime.h>

#define DIM 128

// ---------------------------------------------------------------------------
// K0: v0[k] = sum_j outW0[j,k]*regW[j] ; v1[k] = sum_j outW1[j,k]*regW[128+j]
//     c = regb + dot(outb0, regW[:128]) + dot(outb1, regW[128:])
// ---------------------------------------------------------------------------
__global__ void precompute_v_kernel(const float* __restrict__ outW0,
                                    const float* __restrict__ outW1,
                                    const float* __restrict__ outb0,
                                    const float* __restrict__ outb1,
                                    const float* __restrict__ regW,
                                    const float* __restrict__ regb,
                                    float* __restrict__ vbuf) {
    int t = threadIdx.x;  // 256 threads, 1 block
    if (t < DIM) {
        float s = 0.f;
        #pragma unroll 8
        for (int j = 0; j < DIM; ++j) s = fmaf(outW0[j * DIM + t], regW[j], s);
        vbuf[t] = s;
    } else {
        int k = t - DIM;
        float s = 0.f;
        #pragma unroll 8
        for (int j = 0; j < DIM; ++j) s = fmaf(outW1[j * DIM + k], regW[DIM + j], s);
        vbuf[t] = s;
    }
    if (t == 0) {
        float c = regb[0];
        for (int j = 0; j < DIM; ++j) c += outb0[j] * regW[j] + outb1[j] * regW[DIM + j];
        vbuf[2 * DIM] = c;
    }
}

// ---------------------------------------------------------------------------
// CSR build: histogram -> 3-kernel scan -> fill
// ---------------------------------------------------------------------------
__global__ void hist_kernel(const int* __restrict__ ei, int nedges, int* __restrict__ deg) {
    const int* __restrict__ dst = ei + nedges;
    int i = blockIdx.x * blockDim.x + threadIdx.x;
    int stride = gridDim.x * blockDim.x;
    for (int e = i; e < nedges; e += stride) atomicAdd(&deg[dst[e]], 1);
}

// A: bsum[b] = sum of deg[b*256 .. b*256+255]
__global__ void scan_reduce_kernel(const int* __restrict__ deg, int* __restrict__ bsum, int n) {
    int i = blockIdx.x * 256 + threadIdx.x;
    int v = (i < n) ? deg[i] : 0;
    #pragma unroll
    for (int off = 32; off >= 1; off >>= 1) v += __shfl_down(v, off);
    __shared__ int wsum[4];
    int lane = threadIdx.x & 63, w = threadIdx.x >> 6;
    if (lane == 0) wsum[w] = v;
    __syncthreads();
    if (threadIdx.x == 0) bsum[blockIdx.x] = wsum[0] + wsum[1] + wsum[2] + wsum[3];
}

// B: exclusive scan of bsum[0..nb) in-place (nb <= 1024), one block of 1024
__global__ void scan_blocksums_kernel(int* __restrict__ bsum, int nb) {
    __shared__ int s[1024];
    int t = threadIdx.x;
    s[t] = (t < nb) ? bsum[t] : 0;
    __syncthreads();
    for (int off = 1; off < 1024; off <<= 1) {
        int v = (t >= off) ? s[t - off] : 0;
        __syncthreads();
        s[t] += v;
        __syncthreads();
    }
    if (t < nb) bsum[t] = (t == 0) ? 0 : s[t - 1];
}

// C: rowptr[i] = bsum[blk] + exclusive_scan_within_block(deg); also cursor copy
__global__ void scan_write_kernel(const int* __restrict__ deg, const int* __restrict__ bsum,
                                  int* __restrict__ rowptr, int* __restrict__ cursor,
                                  int n, int total) {
    int i = blockIdx.x * 256 + threadIdx.x;
    int v = (i < n) ? deg[i] : 0;
    int lane = threadIdx.x & 63, w = threadIdx.x >> 6;
    int sv = v;  // inclusive wave scan
    #pragma unroll
    for (int off = 1; off < 64; off <<= 1) {
        int u = __shfl_up(sv, off);
        if (lane >= off) sv += u;
    }
    __shared__ int wsum[4];
    if (lane == 63) wsum[w] = sv;
    __syncthreads();
    int base = bsum[blockIdx.x];
    #pragma unroll
    for (int k = 0; k < 4; ++k)
        if (k < w) base += wsum[k];
    int ex = base + sv - v;
    if (i < n) {
        rowptr[i] = ex;
        cursor[i] = ex;
    }
    if (blockIdx.x == 0 && threadIdx.x == 0) rowptr[n] = total;
}

__global__ void fill_kernel(const int* __restrict__ ei, int nedges,
                            int* __restrict__ cursor, int* __restrict__ eidx) {
    const int* __restrict__ src = ei;
    const int* __restrict__ dst = ei + nedges;
    int i = blockIdx.x * blockDim.x + threadIdx.x;
    int stride = gridDim.x * blockDim.x;
    for (int e = i; e < nedges; e += stride) {
        int s = src[e];
        int d = dst[e];
        int pos = atomicAdd(&cursor[d], 1);
        eidx[pos] = s;
    }
}

// ---------------------------------------------------------------------------
// Gather-side mean aggregation: one wave per dst row, float2 per lane.
// ---------------------------------------------------------------------------
__global__ void aggregate_kernel(const float* __restrict__ xsrc,
                                 const int* __restrict__ rowptr,
                                 const int* __restrict__ eidx,
                                 float* __restrict__ mean, int n) {
    int wid = (blockIdx.x * blockDim.x + threadIdx.x) >> 6;
    int lane = threadIdx.x & 63;
    int nw = (gridDim.x * blockDim.x) >> 6;
    for (int r = wid; r < n; r += nw) {
        int beg = rowptr[r];
        int end = rowptr[r + 1];
        float ax = 0.f, ay = 0.f;
        for (int j = beg; j < end; ++j) {
            int s = eidx[j];   // wave-uniform -> scalar load
            float2 v = *reinterpret_cast<const float2*>(xsrc + (size_t)s * DIM + lane * 2);
            ax += v.x;
            ay += v.y;
        }
        float sc = 1.0f / fmaxf((float)(end - beg), 1.0f);
        float2 o;
        o.x = ax * sc;
        o.y = ay * sc;
        *reinterpret_cast<float2*>(mean + (size_t)r * DIM + lane * 2) = o;
    }
}

// ---------------------------------------------------------------------------
// Fused SAGE hop GEMM:  h[i,:] = relu( mean[i] @ Wl^T + x_dst[i] @ Wr^T + bl )
// MODE 0: store h -> H.   MODE 1: out[i]  = c + dot(h, v).   MODE 2: out[i] += dot(h, v).
// BM=128, BN=128, BK=32; 256 threads; 8x8 micro-tile.
// ---------------------------------------------------------------------------
template <int MODE>
__launch_bounds__(256, 2)
__global__ void sage_gemm_kernel(const float* __restrict__ mean,
                                 const float* __restrict__ xdst,
                                 const float* __restrict__ Wl,
                                 const float* __restrict__ Wr,
                                 const float* __restrict__ bl,
                                 float* __restrict__ H,
                                 const float* __restrict__ v,
                                 const float* __restrict__ cptr,
                                 float* __restrict__ out,
                                 int nrows) {
    __shared__ float As[32][DIM + 4];   // [k][m] transposed A tile
    __shared__ float Bs[32][DIM + 4];   // [k][n] transposed B tile

    const int tid = threadIdx.x;
    const int tx = tid & 15;       // col group: cols tx*8 .. +8
    const int ty = tid >> 4;       // row group: rows ty*8 .. +8
    const int row0 = blockIdx.x * DIM;

    float acc[8][8];
    #pragma unroll
    for (int i = 0; i < 8; ++i)
        #pragma unroll
        for (int j = 0; j < 8; ++j) acc[i][j] = 0.f;

    for (int kt = 0; kt < 8; ++kt) {
        const bool first = (kt < 4);                 // uniform per tile
        const float* __restrict__ Asrc = first ? mean : xdst;
        const float* __restrict__ W = first ? Wl : Wr;
        const int kb = (kt & 3) * 32;

        // stage A: 128 rows x 32 k  (each thread: 4 float4 loads)
        #pragma unroll
        for (int p = 0; p < 4; ++p) {
            int rl = p * 32 + (tid >> 3);
            int kk = (tid & 7) * 4;
            int row = row0 + rl;
            float4 val = make_float4(0.f, 0.f, 0.f, 0.f);
            if (row < nrows) {
                val = *reinterpret_cast<const float4*>(Asrc + (size_t)row * DIM + kb + kk);
            }
            As[kk + 0][rl] = val.x;
            As[kk + 1][rl] = val.y;
            As[kk + 2][rl] = val.z;
            As[kk + 3][rl] = val.w;
        }
        // stage B: Bs[k][j] = W[j][kb+k]
        #pragma unroll
        for (int p = 0; p < 4; ++p) {
            int j = p * 32 + (tid >> 3);
            int kk = (tid & 7) * 4;
            float4 w = *reinterpret_cast<const float4*>(W + j * DIM + kb + kk);
            Bs[kk + 0][j] = w.x;
            Bs[kk + 1][j] = w.y;
            Bs[kk + 2][j] = w.z;
            Bs[kk + 3][j] = w.w;
        }
        __syncthreads();

        #pragma unroll
        for (int k = 0; k < 32; ++k) {
            float4 a0 = *reinterpret_cast<const float4*>(&As[k][ty * 8]);
            float4 a1 = *reinterpret_cast<const float4*>(&As[k][ty * 8 + 4]);
            float4 b0 = *reinterpret_cast<const float4*>(&Bs[k][tx * 8]);
            float4 b1 = *reinterpret_cast<const float4*>(&Bs[k][tx * 8 + 4]);
            float av[8] = {a0.x, a0.y, a0.z, a0.w, a1.x, a1.y, a1.z, a1.w};
            float bv[8] = {b0.x, b0.y, b0.z, b0.w, b1.x, b1.y, b1.z, b1.w};
            #pragma unroll
            for (int i = 0; i < 8; ++i)
                #pragma unroll
                for (int j = 0; j < 8; ++j)
                    acc[i][j] = fmaf(av[i], bv[j], acc[i][j]);
        }
        __syncthreads();
    }

    // bias for this thread's 8 columns
    float blv[8];
    {
        float4 b0 = *reinterpret_cast<const float4*>(bl + tx * 8);
        float4 b1 = *reinterpret_cast<const float4*>(bl + tx * 8 + 4);
        blv[0] = b0.x; blv[1] = b0.y; blv[2] = b0.z; blv[3] = b0.w;
        blv[4] = b1.x; blv[5] = b1.y; blv[6] = b1.z; blv[7] = b1.w;
    }

    if (MODE == 0) {
        #pragma unroll
        for (int i = 0; i < 8; ++i) {
            int row = row0 + ty * 8 + i;
            if (row < nrows) {
                float4 o0, o1;
                o0.x = fmaxf(acc[i][0] + blv[0], 0.f);
                o0.y = fmaxf(acc[i][1] + blv[1], 0.f);
                o0.z = fmaxf(acc[i][2] + blv[2], 0.f);
                o0.w = fmaxf(acc[i][3] + blv[3], 0.f);
                o1.x = fmaxf(acc[i][4] + blv[4], 0.f);
                o1.y = fmaxf(acc[i][5] + blv[5], 0.f);
                o1.z = fmaxf(acc[i][6] + blv[6], 0.f);
                o1.w = fmaxf(acc[i][7] + blv[7], 0.f);
                *reinterpret_cast<float4*>(H + (size_t)row * DIM + tx * 8) = o0;
                *reinterpret_cast<float4*>(H + (size_t)row * DIM + tx * 8 + 4) = o1;
            }
        }
    } else {
        float vv[8];
        {
            float4 v0 = *reinterpret_cast<const float4*>(v + tx * 8);
            float4 v1 = *reinterpret_cast<const float4*>(v + tx * 8 + 4);
            vv[0] = v0.x; vv[1] = v0.y; vv[2] = v0.z; vv[3] = v0.w;
            vv[4] = v1.x; vv[5] = v1.y; vv[6] = v1.z; vv[7] = v1.w;
        }
        float cbase = (MODE == 1) ? cptr[0] : 0.f;
        #pragma unroll
        for (int i = 0; i < 8; ++i) {
            float p = 0.f;
            #pragma unroll
            for (int j = 0; j < 8; ++j)
                p = fmaf(fmaxf(acc[i][j] + blv[j], 0.f), vv[j], p);
            // reduce across the 16 tx lanes (lane bits 0..3)
            p += __shfl_xor(p, 1);
            p += __shfl_xor(p, 2);
            p += __shfl_xor(p, 4);
            p += __shfl_xor(p, 8);
            int row = row0 + ty * 8 + i;
            if (tx == 0 && row < nrows) {
                if (MODE == 1) out[row] = cbase + p;
                else out[row] += p;
            }
        }
    }
}

// ---------------------------------------------------------------------------
extern "C" void kernel_launch(void* const* d_in, const int* in_sizes, int n_in,
                              void* d_out, int out_size, void* d_ws, size_t ws_size,
                              hipStream_t stream) {
    const float* x_user = (const float*)d_in[0];
    const float* x_item = (const float*)d_in[1];
    const int* ei_m0_h0 = (const int*)d_in[2];
    const int* ei_m0_h1 = (const int*)d_in[3];
    const int* ei_m1_h0 = (const int*)d_in[4];
    const int* ei_m1_h1 = (const int*)d_in[5];
    const float* Wl00 = (const float*)d_in[6];
    const float* Wr00 = (const float*)d_in[7];
    const float* Wl01 = (const float*)d_in[8];
    const float* Wr01 = (const float*)d_in[9];
    const float* Wl10 = (const float*)d_in[10];
    const float* Wr10 = (const float*)d_in[11];
    const float* Wl11 = (const float*)d_in[12];
    const float* Wr11 = (const float*)d_in[13];
    const float* outW0 = (const float*)d_in[14];
    const float* outW1 = (const float*)d_in[15];
    const float* bl00 = (const float*)d_in[16];
    const float* bl01 = (const float*)d_in[17];
    const float* bl10 = (const float*)d_in[18];
    const float* bl11 = (const float*)d_in[19];
    const float* outb0 = (const float*)d_in[20];
    const float* outb1 = (const float*)d_in[21];
    const float* regW = (const float*)d_in[22];
    const float* regb = (const float*)d_in[23];

    const int N = in_sizes[0] / DIM;
    const int E = in_sizes[2] / 2;
    float* out = (float*)d_out;

    // workspace layout: mean[N*DIM] f32 | hi[N*DIM] f32 | vbuf[2*DIM+1] f32 |
    //   deg[N] i32 | rowptr[N+1] i32 | cursor[N] i32 | bsum[nb] i32 | eidx[E] i32
    const int nb = (N + 255) / 256;
    float* ws = (float*)d_ws;
    float* mean = ws;
    float* hi = mean + (size_t)N * DIM;
    float* vbuf = hi + (size_t)N * DIM;
    int* deg = (int*)(vbuf + 2 * DIM + 1);
    int* rowptr = deg + N;
    int* cursor = rowptr + N + 1;
    int* bsum = cursor + N;
    int* eidx = bsum + nb;

    precompute_v_kernel<<<1, 256, 0, stream>>>(outW0, outW1, outb0, outb1, regW, regb, vbuf);

    const int gemmBlocks = (N + DIM - 1) / DIM;
    const int edgeBlocks = 1024;
    const int aggBlocks = 2048;

    struct Hop {
        const int* ei;
        const float* xsrc;
        const float* xdst;
        const float *Wl, *Wr, *bl;
        int mode;            // 0: ->hi, 1: ->out (=), 2: ->out (+=)
        const float* v;
    };
    const Hop hops[4] = {
        {ei_m0_h0, x_user, x_item, Wl00, Wr00, bl00, 0, nullptr},
        {ei_m0_h1, hi,     x_user, Wl01, Wr01, bl01, 1, vbuf},
        {ei_m1_h0, x_user, x_item, Wl10, Wr10, bl10, 0, nullptr},
        {ei_m1_h1, hi,     x_user, Wl11, Wr11, bl11, 2, vbuf + DIM},
    };

    for (int h = 0; h < 4; ++h) {
        const Hop& hp = hops[h];
        // CSR build
        hipMemsetAsync(deg, 0, (size_t)N * sizeof(int), stream);
        hist_kernel<<<edgeBlocks, 256, 0, stream>>>(hp.ei, E, deg);
        scan_reduce_kernel<<<nb, 256, 0, stream>>>(deg, bsum, N);
        scan_blocksums_kernel<<<1, 1024, 0, stream>>>(bsum, nb);
        scan_write_kernel<<<nb, 256, 0, stream>>>(deg, bsum, rowptr, cursor, N, E);
        fill_kernel<<<edgeBlocks, 256, 0, stream>>>(hp.ei, E, cursor, eidx);
        // gather-side mean
        aggregate_kernel<<<aggBlocks, 256, 0, stream>>>(hp.xsrc, rowptr, eidx, mean, N);
        // fused GEMM
        if (hp.mode == 0)
            sage_gemm_kernel<0><<<gemmBlocks, 256, 0, stream>>>(mean, hp.xdst, hp.Wl, hp.Wr, hp.bl,
                                                                hi, nullptr, nullptr, nullptr, N);
        else if (hp.mode == 1)
            sage_gemm_kernel<1><<<gemmBlocks, 256, 0, stream>>>(mean, hp.xdst, hp.Wl, hp.Wr, hp.bl,
                                                                nullptr, hp.v, vbuf + 2 * DIM, out, N);
        else
            sage_gemm_kernel<2><<<gemmBlocks, 256, 0, stream>>>(mean, hp.xdst, hp.Wl, hp.Wr, hp.bl,
                                                                nullptr, hp.v, vbuf + 2 * DIM, out, N);
    }
}

// Round 4
// 840.689 us; speedup vs baseline: 3.9389x; 1.4523x over previous
//
#include <hip/hip_runtime.h>

#define DIM 128
typedef unsigned short ushort_t;
typedef short bf16x8 __attribute__((ext_vector_type(8)));
typedef float f32x4 __attribute__((ext_vector_type(4)));

__device__ inline ushort_t f2bf(float f) {
    unsigned int u = __float_as_uint(f);
    unsigned int r = (u + 0x7FFFu + ((u >> 16) & 1u)) >> 16;
    return (ushort_t)r;
}
__device__ inline float bflo2f(unsigned int u) { return __uint_as_float(u << 16); }
__device__ inline float bfhi2f(unsigned int u) { return __uint_as_float(u & 0xFFFF0000u); }

// ---------------------------------------------------------------------------
__global__ void f32_to_bf16_kernel(const float* __restrict__ in, ushort_t* __restrict__ out, int n4) {
    int i = blockIdx.x * blockDim.x + threadIdx.x;
    int stride = gridDim.x * blockDim.x;
    for (; i < n4; i += stride) {
        float4 v = *reinterpret_cast<const float4*>(in + (size_t)i * 4);
        ushort_t o[4] = {f2bf(v.x), f2bf(v.y), f2bf(v.z), f2bf(v.w)};
        *reinterpret_cast<uint2*>(out + (size_t)i * 4) = *reinterpret_cast<uint2*>(o);
    }
}

// Wcat[j][k] (k<128 -> Wl[j][k], else Wr[j][k-128]) as bf16. grid 128 x 256 thr
__global__ void pack_weights_kernel(const float* __restrict__ Wl, const float* __restrict__ Wr,
                                    ushort_t* __restrict__ Wcat) {
    int j = blockIdx.x, k = threadIdx.x;
    float v = (k < DIM) ? Wl[j * DIM + k] : Wr[j * DIM + (k - DIM)];
    Wcat[j * 256 + k] = f2bf(v);
}

// ---------------------------------------------------------------------------
// K0: v0[k] = sum_j outW0[j,k]*regW[j] ; v1[k] = sum_j outW1[j,k]*regW[128+j]
//     c = regb + dot(outb0, regW[:128]) + dot(outb1, regW[128:])
// ---------------------------------------------------------------------------
__global__ void precompute_v_kernel(const float* __restrict__ outW0,
                                    const float* __restrict__ outW1,
                                    const float* __restrict__ outb0,
                                    const float* __restrict__ outb1,
                                    const float* __restrict__ regW,
                                    const float* __restrict__ regb,
                                    float* __restrict__ vbuf) {
    int t = threadIdx.x;
    if (t < DIM) {
        float s = 0.f;
        #pragma unroll 8
        for (int j = 0; j < DIM; ++j) s = fmaf(outW0[j * DIM + t], regW[j], s);
        vbuf[t] = s;
    } else {
        int k = t - DIM;
        float s = 0.f;
        #pragma unroll 8
        for (int j = 0; j < DIM; ++j) s = fmaf(outW1[j * DIM + k], regW[DIM + j], s);
        vbuf[t] = s;
    }
    if (t == 0) {
        float c = regb[0];
        for (int j = 0; j < DIM; ++j) c += outb0[j] * regW[j] + outb1[j] * regW[DIM + j];
        vbuf[2 * DIM] = c;
    }
}

// ---------------------------------------------------------------------------
// CSR build: histogram -> 3-kernel scan -> fill
// ---------------------------------------------------------------------------
__global__ void hist_kernel(const int* __restrict__ ei, int nedges, int* __restrict__ deg) {
    const int* __restrict__ dst = ei + nedges;
    int i = blockIdx.x * blockDim.x + threadIdx.x;
    int stride = gridDim.x * blockDim.x;
    for (int e = i; e < nedges; e += stride) atomicAdd(&deg[dst[e]], 1);
}

__global__ void scan_reduce_kernel(const int* __restrict__ deg, int* __restrict__ bsum, int n) {
    int i = blockIdx.x * 256 + threadIdx.x;
    int v = (i < n) ? deg[i] : 0;
    #pragma unroll
    for (int off = 32; off >= 1; off >>= 1) v += __shfl_down(v, off);
    __shared__ int wsum[4];
    int lane = threadIdx.x & 63, w = threadIdx.x >> 6;
    if (lane == 0) wsum[w] = v;
    __syncthreads();
    if (threadIdx.x == 0) bsum[blockIdx.x] = wsum[0] + wsum[1] + wsum[2] + wsum[3];
}

__global__ void scan_blocksums_kernel(int* __restrict__ bsum, int nb) {
    __shared__ int s[1024];
    int t = threadIdx.x;
    s[t] = (t < nb) ? bsum[t] : 0;
    __syncthreads();
    for (int off = 1; off < 1024; off <<= 1) {
        int v = (t >= off) ? s[t - off] : 0;
        __syncthreads();
        s[t] += v;
        __syncthreads();
    }
    if (t < nb) bsum[t] = (t == 0) ? 0 : s[t - 1];
}

__global__ void scan_write_kernel(const int* __restrict__ deg, const int* __restrict__ bsum,
                                  int* __restrict__ rowptr, int* __restrict__ cursor,
                                  int n, int total) {
    int i = blockIdx.x * 256 + threadIdx.x;
    int v = (i < n) ? deg[i] : 0;
    int lane = threadIdx.x & 63, w = threadIdx.x >> 6;
    int sv = v;
    #pragma unroll
    for (int off = 1; off < 64; off <<= 1) {
        int u = __shfl_up(sv, off);
        if (lane >= off) sv += u;
    }
    __shared__ int wsum[4];
    if (lane == 63) wsum[w] = sv;
    __syncthreads();
    int base = bsum[blockIdx.x];
    #pragma unroll
    for (int k = 0; k < 4; ++k)
        if (k < w) base += wsum[k];
    int ex = base + sv - v;
    if (i < n) {
        rowptr[i] = ex;
        cursor[i] = ex;
    }
    if (blockIdx.x == 0 && threadIdx.x == 0) rowptr[n] = total;
}

__global__ void fill_kernel(const int* __restrict__ ei, int nedges,
                            int* __restrict__ cursor, int* __restrict__ eidx) {
    const int* __restrict__ src = ei;
    const int* __restrict__ dst = ei + nedges;
    int i = blockIdx.x * blockDim.x + threadIdx.x;
    int stride = gridDim.x * blockDim.x;
    for (int e = i; e < nedges; e += stride) {
        int s = src[e];
        int d = dst[e];
        int pos = atomicAdd(&cursor[d], 1);
        eidx[pos] = s;
    }
}

// ---------------------------------------------------------------------------
// Gather-side mean (bf16 in, f32 accum, bf16 out): one wave per dst row.
// Lane handles cols lane*2, lane*2+1 (uint = 2 bf16 -> 256B per row).
// ---------------------------------------------------------------------------
__global__ void aggregate_kernel(const ushort_t* __restrict__ xsrc,
                                 const int* __restrict__ rowptr,
                                 const int* __restrict__ eidx,
                                 ushort_t* __restrict__ mean, int n) {
    int wid = (blockIdx.x * blockDim.x + threadIdx.x) >> 6;
    int lane = threadIdx.x & 63;
    int nw = (gridDim.x * blockDim.x) >> 6;
    for (int r = wid; r < n; r += nw) {
        int beg = rowptr[r];
        int end = rowptr[r + 1];
        float ax = 0.f, ay = 0.f;
        for (int j = beg; j < end; ++j) {
            int s = eidx[j];   // wave-uniform
            unsigned int u = *reinterpret_cast<const unsigned int*>(xsrc + (size_t)s * DIM + lane * 2);
            ax += bflo2f(u);
            ay += bfhi2f(u);
        }
        float sc = 1.0f / fmaxf((float)(end - beg), 1.0f);
        unsigned int o = (unsigned int)f2bf(ax * sc) | ((unsigned int)f2bf(ay * sc) << 16);
        *reinterpret_cast<unsigned int*>(mean + (size_t)r * DIM + lane * 2) = o;
    }
}

// ---------------------------------------------------------------------------
// MFMA SAGE hop GEMM (bf16 in, f32 accum):
//   h[i,:] = relu( [mean | xdst][i,:] @ Wcat^T + bl )      (K=256, Ncols=128)
// MODE 0: H[i,:] = bf16(h).  MODE 1: out[i] = c + dot(h,v).  MODE 2: out[i] += dot(h,v).
// 256 thr = 4 waves (2x2); wave tile 64x64 = 4x4 frags of 16x16; BK=32.
// ---------------------------------------------------------------------------
template <int MODE>
__launch_bounds__(256, 2)
__global__ void sage_gemm_mfma(const ushort_t* __restrict__ A0,   // mean bf16 [N][128]
                               const ushort_t* __restrict__ A1,   // xdst bf16 [N][128]
                               const ushort_t* __restrict__ Wcat, // [128][256] bf16
                               const float* __restrict__ bl,
                               ushort_t* __restrict__ H,
                               const float* __restrict__ v,
                               const float* __restrict__ cptr,
                               float* __restrict__ out,
                               int nrows) {
    __shared__ ushort_t As[128][40];   // pad 8 -> row stride 80B (16B-aligned, conflict-free)
    __shared__ ushort_t Bs[128][40];   // Bs[j][k] : j = output col
    __shared__ float red[2][128];

    const int tid = threadIdx.x;
    const int lane = tid & 63;
    const int w = tid >> 6;
    const int wr = w >> 1, wc = w & 1;
    const int lr = lane & 15;
    const int lk = (lane >> 4) * 8;
    const int row0 = blockIdx.x * 128;

    f32x4 acc[4][4];
    #pragma unroll
    for (int m = 0; m < 4; ++m)
        #pragma unroll
        for (int n = 0; n < 4; ++n)
            acc[m][n] = (f32x4){0.f, 0.f, 0.f, 0.f};

    for (int kt = 0; kt < 8; ++kt) {
        const int kb = kt * 32;
        const ushort_t* __restrict__ Asrc = (kb < DIM) ? A0 : A1;
        const int kbb = kb & (DIM - 1);

        #pragma unroll
        for (int p = 0; p < 2; ++p) {
            int idx = p * 256 + tid;
            int r = idx >> 2, c = idx & 3;
            int grow = row0 + r;
            uint4 val = make_uint4(0u, 0u, 0u, 0u);
            if (grow < nrows)
                val = *reinterpret_cast<const uint4*>(Asrc + (size_t)grow * DIM + kbb + c * 8);
            *reinterpret_cast<uint4*>(&As[r][c * 8]) = val;
        }
        #pragma unroll
        for (int p = 0; p < 2; ++p) {
            int idx = p * 256 + tid;
            int j = idx >> 2, c = idx & 3;
            uint4 val = *reinterpret_cast<const uint4*>(Wcat + j * 256 + kb + c * 8);
            *reinterpret_cast<uint4*>(&Bs[j][c * 8]) = val;
        }
        __syncthreads();

        bf16x8 af[4], bfm[4];
        #pragma unroll
        for (int m = 0; m < 4; ++m)
            af[m] = *reinterpret_cast<const bf16x8*>(&As[wr * 64 + m * 16 + lr][lk]);
        #pragma unroll
        for (int n = 0; n < 4; ++n)
            bfm[n] = *reinterpret_cast<const bf16x8*>(&Bs[wc * 64 + n * 16 + lr][lk]);
        #pragma unroll
        for (int m = 0; m < 4; ++m)
            #pragma unroll
            for (int n = 0; n < 4; ++n)
                acc[m][n] = __builtin_amdgcn_mfma_f32_16x16x32_bf16(af[m], bfm[n], acc[m][n], 0, 0, 0);
        __syncthreads();
    }

    // C/D mapping (m89-verified): col = lane&15, row = (lane>>4)*4 + reg
    if (MODE == 0) {
        float blc[4];
        #pragma unroll
        for (int n = 0; n < 4; ++n) blc[n] = bl[wc * 64 + n * 16 + lr];
        #pragma unroll
        for (int m = 0; m < 4; ++m) {
            #pragma unroll
            for (int reg = 0; reg < 4; ++reg) {
                int row = row0 + wr * 64 + m * 16 + (lane >> 4) * 4 + reg;
                if (row < nrows) {
                    #pragma unroll
                    for (int n = 0; n < 4; ++n) {
                        int col = wc * 64 + n * 16 + lr;
                        H[(size_t)row * DIM + col] = f2bf(fmaxf(acc[m][n][reg] + blc[n], 0.f));
                    }
                }
            }
        }
    } else {
        float blc[4], vc[4];
        #pragma unroll
        for (int n = 0; n < 4; ++n) {
            int col = wc * 64 + n * 16 + lr;
            blc[n] = bl[col];
            vc[n] = v[col];
        }
        #pragma unroll
        for (int m = 0; m < 4; ++m) {
            float rp[4] = {0.f, 0.f, 0.f, 0.f};
            #pragma unroll
            for (int n = 0; n < 4; ++n)
                #pragma unroll
                for (int reg = 0; reg < 4; ++reg)
                    rp[reg] = fmaf(fmaxf(acc[m][n][reg] + blc[n], 0.f), vc[n], rp[reg]);
            #pragma unroll
            for (int reg = 0; reg < 4; ++reg) {
                float p = rp[reg];
                p += __shfl_xor(p, 1);
                p += __shfl_xor(p, 2);
                p += __shfl_xor(p, 4);
                p += __shfl_xor(p, 8);
                if (lr == 0)
                    red[wc][wr * 64 + m * 16 + (lane >> 4) * 4 + reg] = p;
            }
        }
        __syncthreads();
        if (tid < 128) {
            int row = row0 + tid;
            if (row < nrows) {
                float s = red[0][tid] + red[1][tid];
                if (MODE == 1) out[row] = cptr[0] + s;
                else out[row] += s;
            }
        }
    }
}

// ---------------------------------------------------------------------------
extern "C" void kernel_launch(void* const* d_in, const int* in_sizes, int n_in,
                              void* d_out, int out_size, void* d_ws, size_t ws_size,
                              hipStream_t stream) {
    const float* x_user = (const float*)d_in[0];
    const float* x_item = (const float*)d_in[1];
    const int* ei_m0_h0 = (const int*)d_in[2];
    const int* ei_m0_h1 = (const int*)d_in[3];
    const int* ei_m1_h0 = (const int*)d_in[4];
    const int* ei_m1_h1 = (const int*)d_in[5];
    const float* Wl00 = (const float*)d_in[6];
    const float* Wr00 = (const float*)d_in[7];
    const float* Wl01 = (const float*)d_in[8];
    const float* Wr01 = (const float*)d_in[9];
    const float* Wl10 = (const float*)d_in[10];
    const float* Wr10 = (const float*)d_in[11];
    const float* Wl11 = (const float*)d_in[12];
    const float* Wr11 = (const float*)d_in[13];
    const float* outW0 = (const float*)d_in[14];
    const float* outW1 = (const float*)d_in[15];
    const float* bl00 = (const float*)d_in[16];
    const float* bl01 = (const float*)d_in[17];
    const float* bl10 = (const float*)d_in[18];
    const float* bl11 = (const float*)d_in[19];
    const float* outb0 = (const float*)d_in[20];
    const float* outb1 = (const float*)d_in[21];
    const float* regW = (const float*)d_in[22];
    const float* regb = (const float*)d_in[23];

    const int N = in_sizes[0] / DIM;
    const int E = in_sizes[2] / 2;
    float* out = (float*)d_out;

    // ws layout: xbu | xbi | meanb | hib (bf16, N*128 each) | Wcat (4*128*256 bf16)
    //            | vbuf f32[257] | deg | rowptr | cursor | bsum | eidx (ints)
    const int nb = (N + 255) / 256;
    ushort_t* xbu = (ushort_t*)d_ws;
    ushort_t* xbi = xbu + (size_t)N * DIM;
    ushort_t* meanb = xbi + (size_t)N * DIM;
    ushort_t* hib = meanb + (size_t)N * DIM;
    ushort_t* Wcat = hib + (size_t)N * DIM;
    float* vbuf = (float*)(Wcat + 4 * 128 * 256);
    int* deg = (int*)(vbuf + 2 * DIM + 1);
    int* rowptr = deg + N;
    int* cursor = rowptr + N + 1;
    int* bsum = cursor + N;
    int* eidx = bsum + nb;

    // one-time conversions
    f32_to_bf16_kernel<<<2048, 256, 0, stream>>>(x_user, xbu, N * DIM / 4);
    f32_to_bf16_kernel<<<2048, 256, 0, stream>>>(x_item, xbi, N * DIM / 4);
    pack_weights_kernel<<<128, 256, 0, stream>>>(Wl00, Wr00, Wcat);
    pack_weights_kernel<<<128, 256, 0, stream>>>(Wl01, Wr01, Wcat + 1 * 128 * 256);
    pack_weights_kernel<<<128, 256, 0, stream>>>(Wl10, Wr10, Wcat + 2 * 128 * 256);
    pack_weights_kernel<<<128, 256, 0, stream>>>(Wl11, Wr11, Wcat + 3 * 128 * 256);
    precompute_v_kernel<<<1, 256, 0, stream>>>(outW0, outW1, outb0, outb1, regW, regb, vbuf);

    const int gemmBlocks = (N + 127) / 128;
    const int edgeBlocks = 1024;
    const int aggBlocks = 2048;

    struct Hop {
        const int* ei;
        const ushort_t* xsrc;
        const ushort_t* xdst;
        const ushort_t* W;
        const float* bl;
        int mode;
        const float* v;
    };
    const Hop hops[4] = {
        {ei_m0_h0, xbu, xbi, Wcat + 0 * 32768, bl00, 0, nullptr},
        {ei_m0_h1, hib, xbu, Wcat + 1 * 32768, bl01, 1, vbuf},
        {ei_m1_h0, xbu, xbi, Wcat + 2 * 32768, bl10, 0, nullptr},
        {ei_m1_h1, hib, xbu, Wcat + 3 * 32768, bl11, 2, vbuf + DIM},
    };

    for (int h = 0; h < 4; ++h) {
        const Hop& hp = hops[h];
        hipMemsetAsync(deg, 0, (size_t)N * sizeof(int), stream);
        hist_kernel<<<edgeBlocks, 256, 0, stream>>>(hp.ei, E, deg);
        scan_reduce_kernel<<<nb, 256, 0, stream>>>(deg, bsum, N);
        scan_blocksums_kernel<<<1, 1024, 0, stream>>>(bsum, nb);
        scan_write_kernel<<<nb, 256, 0, stream>>>(deg, bsum, rowptr, cursor, N, E);
        fill_kernel<<<edgeBlocks, 256, 0, stream>>>(hp.ei, E, cursor, eidx);
        aggregate_kernel<<<aggBlocks, 256, 0, stream>>>(hp.xsrc, rowptr, eidx, meanb, N);
        if (hp.mode == 0)
            sage_gemm_mfma<0><<<gemmBlocks, 256, 0, stream>>>(meanb, hp.xdst, hp.W, hp.bl,
                                                              hib, nullptr, nullptr, nullptr, N);
        else if (hp.mode == 1)
            sage_gemm_mfma<1><<<gemmBlocks, 256, 0, stream>>>(meanb, hp.xdst, hp.W, hp.bl,
                                                              nullptr, hp.v, vbuf + 2 * DIM, out, N);
        else
            sage_gemm_mfma<2><<<gemmBlocks, 256, 0, stream>>>(meanb, hp.xdst, hp.W, hp.bl,
                                                              nullptr, hp.v, vbuf + 2 * DIM, out, N);
    }
}

// Round 5
// 716.267 us; speedup vs baseline: 4.6231x; 1.1737x over previous
//
#include <hip/hip_runtime.h>

#define DIM 128
typedef unsigned short ushort_t;
typedef short bf16x8 __attribute__((ext_vector_type(8)));
typedef float f32x4 __attribute__((ext_vector_type(4)));

__device__ inline ushort_t f2bf(float f) {
    unsigned int u = __float_as_uint(f);
    unsigned int r = (u + 0x7FFFu + ((u >> 16) & 1u)) >> 16;
    return (ushort_t)r;
}
__device__ inline unsigned int pack2bf(float lo, float hi) {
    return (unsigned int)f2bf(lo) | ((unsigned int)f2bf(hi) << 16);
}
__device__ inline float bflo2f(unsigned int u) { return __uint_as_float(u << 16); }
__device__ inline float bfhi2f(unsigned int u) { return __uint_as_float(u & 0xFFFF0000u); }

// ---------------------------------------------------------------------------
__global__ void f32_to_bf16_kernel(const float* __restrict__ in, ushort_t* __restrict__ out, int n4) {
    int i = blockIdx.x * blockDim.x + threadIdx.x;
    int stride = gridDim.x * blockDim.x;
    for (; i < n4; i += stride) {
        float4 v = *reinterpret_cast<const float4*>(in + (size_t)i * 4);
        ushort_t o[4] = {f2bf(v.x), f2bf(v.y), f2bf(v.z), f2bf(v.w)};
        *reinterpret_cast<uint2*>(out + (size_t)i * 4) = *reinterpret_cast<uint2*>(o);
    }
}

// Wcat[j][k] (k<128 -> Wl[j][k], else Wr[j][k-128]) as bf16. grid 128 x 256 thr
__global__ void pack_weights_kernel(const float* __restrict__ Wl, const float* __restrict__ Wr,
                                    ushort_t* __restrict__ Wcat) {
    int j = blockIdx.x, k = threadIdx.x;
    float v = (k < DIM) ? Wl[j * DIM + k] : Wr[j * DIM + (k - DIM)];
    Wcat[j * 256 + k] = f2bf(v);
}

// ---------------------------------------------------------------------------
__global__ void precompute_v_kernel(const float* __restrict__ outW0,
                                    const float* __restrict__ outW1,
                                    const float* __restrict__ outb0,
                                    const float* __restrict__ outb1,
                                    const float* __restrict__ regW,
                                    const float* __restrict__ regb,
                                    float* __restrict__ vbuf) {
    int t = threadIdx.x;
    if (t < DIM) {
        float s = 0.f;
        #pragma unroll 8
        for (int j = 0; j < DIM; ++j) s = fmaf(outW0[j * DIM + t], regW[j], s);
        vbuf[t] = s;
    } else {
        int k = t - DIM;
        float s = 0.f;
        #pragma unroll 8
        for (int j = 0; j < DIM; ++j) s = fmaf(outW1[j * DIM + k], regW[DIM + j], s);
        vbuf[t] = s;
    }
    if (t == 0) {
        float c = regb[0];
        for (int j = 0; j < DIM; ++j) c += outb0[j] * regW[j] + outb1[j] * regW[DIM + j];
        vbuf[2 * DIM] = c;
    }
}

// ---------------------------------------------------------------------------
// Batched CSR build over 4 edge lists: histogram -> 512-thread 3-stage scan -> fill
// deg/rowptr/cursor are length 4N(+1); eidx is 4E; scan is over concat -> global offsets.
// ---------------------------------------------------------------------------
struct EdgePtrs { const int* e[4]; };

__global__ void hist4_kernel(EdgePtrs eps, int nedges, int* __restrict__ deg, int N) {
    int list = blockIdx.y;
    const int* __restrict__ dst = eps.e[list] + nedges;
    int* __restrict__ d = deg + (size_t)list * N;
    int i = blockIdx.x * blockDim.x + threadIdx.x;
    int stride = gridDim.x * blockDim.x;
    for (int e = i; e < nedges; e += stride) atomicAdd(&d[dst[e]], 1);
}

// A: bsum[b] = sum of deg[b*512 .. b*512+511]
__global__ void scan_reduce_kernel(const int* __restrict__ deg, int* __restrict__ bsum, int n) {
    int i = blockIdx.x * 512 + threadIdx.x;
    int v = (i < n) ? deg[i] : 0;
    #pragma unroll
    for (int off = 32; off >= 1; off >>= 1) v += __shfl_down(v, off);
    __shared__ int wsum[8];
    int lane = threadIdx.x & 63, w = threadIdx.x >> 6;
    if (lane == 0) wsum[w] = v;
    __syncthreads();
    if (threadIdx.x == 0) {
        int s = 0;
        #pragma unroll
        for (int k = 0; k < 8; ++k) s += wsum[k];
        bsum[blockIdx.x] = s;
    }
}

// B: exclusive scan of bsum[0..nb) in-place (nb <= 1024)
__global__ void scan_blocksums_kernel(int* __restrict__ bsum, int nb) {
    __shared__ int s[1024];
    int t = threadIdx.x;
    s[t] = (t < nb) ? bsum[t] : 0;
    __syncthreads();
    for (int off = 1; off < 1024; off <<= 1) {
        int v = (t >= off) ? s[t - off] : 0;
        __syncthreads();
        s[t] += v;
        __syncthreads();
    }
    if (t < nb) bsum[t] = (t == 0) ? 0 : s[t - 1];
}

// C: rowptr[i] = bsum[blk] + exclusive_scan_within_block(deg); cursor copy
__global__ void scan_write_kernel(const int* __restrict__ deg, const int* __restrict__ bsum,
                                  int* __restrict__ rowptr, int* __restrict__ cursor,
                                  int n, int total) {
    int i = blockIdx.x * 512 + threadIdx.x;
    int v = (i < n) ? deg[i] : 0;
    int lane = threadIdx.x & 63, w = threadIdx.x >> 6;
    int sv = v;
    #pragma unroll
    for (int off = 1; off < 64; off <<= 1) {
        int u = __shfl_up(sv, off);
        if (lane >= off) sv += u;
    }
    __shared__ int wsum[8];
    if (lane == 63) wsum[w] = sv;
    __syncthreads();
    int base = bsum[blockIdx.x];
    #pragma unroll
    for (int k = 0; k < 8; ++k)
        if (k < w) base += wsum[k];
    int ex = base + sv - v;
    if (i < n) {
        rowptr[i] = ex;
        cursor[i] = ex;
    }
    if (blockIdx.x == 0 && threadIdx.x == 0) rowptr[n] = total;
}

__global__ void fill4_kernel(EdgePtrs eps, int nedges,
                             int* __restrict__ cursor, int* __restrict__ eidx, int N) {
    int list = blockIdx.y;
    const int* __restrict__ src = eps.e[list];
    const int* __restrict__ dst = eps.e[list] + nedges;
    int* __restrict__ cur = cursor + (size_t)list * N;
    int i = blockIdx.x * blockDim.x + threadIdx.x;
    int stride = gridDim.x * blockDim.x;
    for (int e = i; e < nedges; e += stride) {
        int s = src[e];
        int d = dst[e];
        int pos = atomicAdd(&cur[d], 1);
        eidx[pos] = s;
    }
}

// ---------------------------------------------------------------------------
// Gather-side mean, 4-edge MLP: one wave per row; sub-group s (16 lanes, uint4
// = 16B = 8 bf16 per lane) handles edges j = beg + it*4 + s. Final xor-reduce
// over sub-groups, sub 0 writes the bf16 row.
// ---------------------------------------------------------------------------
__global__ void aggregate_kernel(const ushort_t* __restrict__ xsrc,
                                 const int* __restrict__ rowptr,
                                 const int* __restrict__ eidx,
                                 ushort_t* __restrict__ mean, int n) {
    int wid = (blockIdx.x * blockDim.x + threadIdx.x) >> 6;
    int lane = threadIdx.x & 63;
    int nw = (gridDim.x * blockDim.x) >> 6;
    const int sub = lane >> 4;   // edge slot 0..3
    const int lr = lane & 15;    // 16B column slot
    for (int r = wid; r < n; r += nw) {
        int beg = rowptr[r];
        int end = rowptr[r + 1];
        int deg = end - beg;
        float a[8] = {0.f, 0.f, 0.f, 0.f, 0.f, 0.f, 0.f, 0.f};
        int nit = (deg + 3) >> 2;
        for (int it = 0; it < nit; ++it) {
            int j = beg + it * 4 + sub;
            if (j < end) {
                int s = eidx[j];
                uint4 u = *reinterpret_cast<const uint4*>(xsrc + (size_t)s * DIM + lr * 8);
                a[0] += bflo2f(u.x); a[1] += bfhi2f(u.x);
                a[2] += bflo2f(u.y); a[3] += bfhi2f(u.y);
                a[4] += bflo2f(u.z); a[5] += bfhi2f(u.z);
                a[6] += bflo2f(u.w); a[7] += bfhi2f(u.w);
            }
        }
        #pragma unroll
        for (int k = 0; k < 8; ++k) {
            a[k] += __shfl_xor(a[k], 16);
            a[k] += __shfl_xor(a[k], 32);
        }
        if (sub == 0) {
            float sc = 1.0f / fmaxf((float)deg, 1.0f);
            uint4 o;
            o.x = pack2bf(a[0] * sc, a[1] * sc);
            o.y = pack2bf(a[2] * sc, a[3] * sc);
            o.z = pack2bf(a[4] * sc, a[5] * sc);
            o.w = pack2bf(a[6] * sc, a[7] * sc);
            *reinterpret_cast<uint4*>(mean + (size_t)r * DIM + lr * 8) = o;
        }
    }
}

// ---------------------------------------------------------------------------
// MFMA SAGE hop GEMM (bf16 in, f32 accum):
//   h[i,:] = relu( [mean | xdst][i,:] @ Wcat^T + bl )      (K=256, Ncols=128)
// MODE 0: H[i,:] = bf16(h).  MODE 1: out[i] = c + dot(h,v).  MODE 2: out[i] += dot(h,v).
// ---------------------------------------------------------------------------
template <int MODE>
__launch_bounds__(256, 2)
__global__ void sage_gemm_mfma(const ushort_t* __restrict__ A0,
                               const ushort_t* __restrict__ A1,
                               const ushort_t* __restrict__ Wcat,
                               const float* __restrict__ bl,
                               ushort_t* __restrict__ H,
                               const float* __restrict__ v,
                               const float* __restrict__ cptr,
                               float* __restrict__ out,
                               int nrows) {
    __shared__ ushort_t As[128][40];
    __shared__ ushort_t Bs[128][40];
    __shared__ float red[2][128];

    const int tid = threadIdx.x;
    const int lane = tid & 63;
    const int w = tid >> 6;
    const int wr = w >> 1, wc = w & 1;
    const int lr = lane & 15;
    const int lk = (lane >> 4) * 8;
    const int row0 = blockIdx.x * 128;

    f32x4 acc[4][4];
    #pragma unroll
    for (int m = 0; m < 4; ++m)
        #pragma unroll
        for (int n = 0; n < 4; ++n)
            acc[m][n] = (f32x4){0.f, 0.f, 0.f, 0.f};

    for (int kt = 0; kt < 8; ++kt) {
        const int kb = kt * 32;
        const ushort_t* __restrict__ Asrc = (kb < DIM) ? A0 : A1;
        const int kbb = kb & (DIM - 1);

        #pragma unroll
        for (int p = 0; p < 2; ++p) {
            int idx = p * 256 + tid;
            int r = idx >> 2, c = idx & 3;
            int grow = row0 + r;
            uint4 val = make_uint4(0u, 0u, 0u, 0u);
            if (grow < nrows)
                val = *reinterpret_cast<const uint4*>(Asrc + (size_t)grow * DIM + kbb + c * 8);
            *reinterpret_cast<uint4*>(&As[r][c * 8]) = val;
        }
        #pragma unroll
        for (int p = 0; p < 2; ++p) {
            int idx = p * 256 + tid;
            int j = idx >> 2, c = idx & 3;
            uint4 val = *reinterpret_cast<const uint4*>(Wcat + j * 256 + kb + c * 8);
            *reinterpret_cast<uint4*>(&Bs[j][c * 8]) = val;
        }
        __syncthreads();

        bf16x8 af[4], bfm[4];
        #pragma unroll
        for (int m = 0; m < 4; ++m)
            af[m] = *reinterpret_cast<const bf16x8*>(&As[wr * 64 + m * 16 + lr][lk]);
        #pragma unroll
        for (int n = 0; n < 4; ++n)
            bfm[n] = *reinterpret_cast<const bf16x8*>(&Bs[wc * 64 + n * 16 + lr][lk]);
        #pragma unroll
        for (int m = 0; m < 4; ++m)
            #pragma unroll
            for (int n = 0; n < 4; ++n)
                acc[m][n] = __builtin_amdgcn_mfma_f32_16x16x32_bf16(af[m], bfm[n], acc[m][n], 0, 0, 0);
        __syncthreads();
    }

    if (MODE == 0) {
        float blc[4];
        #pragma unroll
        for (int n = 0; n < 4; ++n) blc[n] = bl[wc * 64 + n * 16 + lr];
        #pragma unroll
        for (int m = 0; m < 4; ++m) {
            #pragma unroll
            for (int reg = 0; reg < 4; ++reg) {
                int row = row0 + wr * 64 + m * 16 + (lane >> 4) * 4 + reg;
                if (row < nrows) {
                    #pragma unroll
                    for (int n = 0; n < 4; ++n) {
                        int col = wc * 64 + n * 16 + lr;
                        H[(size_t)row * DIM + col] = f2bf(fmaxf(acc[m][n][reg] + blc[n], 0.f));
                    }
                }
            }
        }
    } else {
        float blc[4], vc[4];
        #pragma unroll
        for (int n = 0; n < 4; ++n) {
            int col = wc * 64 + n * 16 + lr;
            blc[n] = bl[col];
            vc[n] = v[col];
        }
        #pragma unroll
        for (int m = 0; m < 4; ++m) {
            float rp[4] = {0.f, 0.f, 0.f, 0.f};
            #pragma unroll
            for (int n = 0; n < 4; ++n)
                #pragma unroll
                for (int reg = 0; reg < 4; ++reg)
                    rp[reg] = fmaf(fmaxf(acc[m][n][reg] + blc[n], 0.f), vc[n], rp[reg]);
            #pragma unroll
            for (int reg = 0; reg < 4; ++reg) {
                float p = rp[reg];
                p += __shfl_xor(p, 1);
                p += __shfl_xor(p, 2);
                p += __shfl_xor(p, 4);
                p += __shfl_xor(p, 8);
                if (lr == 0)
                    red[wc][wr * 64 + m * 16 + (lane >> 4) * 4 + reg] = p;
            }
        }
        __syncthreads();
        if (tid < 128) {
            int row = row0 + tid;
            if (row < nrows) {
                float s = red[0][tid] + red[1][tid];
                if (MODE == 1) out[row] = cptr[0] + s;
                else out[row] += s;
            }
        }
    }
}

// ---------------------------------------------------------------------------
extern "C" void kernel_launch(void* const* d_in, const int* in_sizes, int n_in,
                              void* d_out, int out_size, void* d_ws, size_t ws_size,
                              hipStream_t stream) {
    const float* x_user = (const float*)d_in[0];
    const float* x_item = (const float*)d_in[1];
    const int* ei_m0_h0 = (const int*)d_in[2];
    const int* ei_m0_h1 = (const int*)d_in[3];
    const int* ei_m1_h0 = (const int*)d_in[4];
    const int* ei_m1_h1 = (const int*)d_in[5];
    const float* Wl00 = (const float*)d_in[6];
    const float* Wr00 = (const float*)d_in[7];
    const float* Wl01 = (const float*)d_in[8];
    const float* Wr01 = (const float*)d_in[9];
    const float* Wl10 = (const float*)d_in[10];
    const float* Wr10 = (const float*)d_in[11];
    const float* Wl11 = (const float*)d_in[12];
    const float* Wr11 = (const float*)d_in[13];
    const float* outW0 = (const float*)d_in[14];
    const float* outW1 = (const float*)d_in[15];
    const float* bl00 = (const float*)d_in[16];
    const float* bl01 = (const float*)d_in[17];
    const float* bl10 = (const float*)d_in[18];
    const float* bl11 = (const float*)d_in[19];
    const float* outb0 = (const float*)d_in[20];
    const float* outb1 = (const float*)d_in[21];
    const float* regW = (const float*)d_in[22];
    const float* regb = (const float*)d_in[23];

    const int N = in_sizes[0] / DIM;
    const int E = in_sizes[2] / 2;
    float* out = (float*)d_out;

    // ws: xbu | xbi | meanb | hib (bf16 N*128 each) | Wcat (4*32768 bf16)
    //     | vbuf f32[257] | deg[4N] | rowptr[4N+1] | cursor[4N] | bsum | eidx[4E]
    const int n4 = 4 * N;
    const int nb = (n4 + 511) / 512;
    ushort_t* xbu = (ushort_t*)d_ws;
    ushort_t* xbi = xbu + (size_t)N * DIM;
    ushort_t* meanb = xbi + (size_t)N * DIM;
    ushort_t* hib = meanb + (size_t)N * DIM;
    ushort_t* Wcat = hib + (size_t)N * DIM;
    float* vbuf = (float*)(Wcat + 4 * 128 * 256);
    int* deg = (int*)(vbuf + 2 * DIM + 1);
    int* rowptr = deg + n4;
    int* cursor = rowptr + n4 + 1;
    int* bsum = cursor + n4;
    int* eidx = bsum + nb;

    // one-time conversions
    f32_to_bf16_kernel<<<2048, 256, 0, stream>>>(x_user, xbu, N * DIM / 4);
    f32_to_bf16_kernel<<<2048, 256, 0, stream>>>(x_item, xbi, N * DIM / 4);
    pack_weights_kernel<<<128, 256, 0, stream>>>(Wl00, Wr00, Wcat);
    pack_weights_kernel<<<128, 256, 0, stream>>>(Wl01, Wr01, Wcat + 1 * 32768);
    pack_weights_kernel<<<128, 256, 0, stream>>>(Wl10, Wr10, Wcat + 2 * 32768);
    pack_weights_kernel<<<128, 256, 0, stream>>>(Wl11, Wr11, Wcat + 3 * 32768);
    precompute_v_kernel<<<1, 256, 0, stream>>>(outW0, outW1, outb0, outb1, regW, regb, vbuf);

    // batched CSR build for all 4 edge lists (independent of features)
    EdgePtrs eps;
    eps.e[0] = ei_m0_h0; eps.e[1] = ei_m0_h1; eps.e[2] = ei_m1_h0; eps.e[3] = ei_m1_h1;
    hipMemsetAsync(deg, 0, (size_t)n4 * sizeof(int), stream);
    hist4_kernel<<<dim3(512, 4), 256, 0, stream>>>(eps, E, deg, N);
    scan_reduce_kernel<<<nb, 512, 0, stream>>>(deg, bsum, n4);
    scan_blocksums_kernel<<<1, 1024, 0, stream>>>(bsum, nb);
    scan_write_kernel<<<nb, 512, 0, stream>>>(deg, bsum, rowptr, cursor, n4, 4 * E);
    fill4_kernel<<<dim3(512, 4), 256, 0, stream>>>(eps, E, cursor, eidx, N);

    const int gemmBlocks = (N + 127) / 128;
    const int aggBlocks = 2048;

    struct Hop {
        const ushort_t* xsrc;
        const ushort_t* xdst;
        const ushort_t* W;
        const float* bl;
        int mode;
        const float* v;
    };
    const Hop hops[4] = {
        {xbu, xbi, Wcat + 0 * 32768, bl00, 0, nullptr},
        {hib, xbu, Wcat + 1 * 32768, bl01, 1, vbuf},
        {xbu, xbi, Wcat + 2 * 32768, bl10, 0, nullptr},
        {hib, xbu, Wcat + 3 * 32768, bl11, 2, vbuf + DIM},
    };

    for (int h = 0; h < 4; ++h) {
        const Hop& hp = hops[h];
        aggregate_kernel<<<aggBlocks, 256, 0, stream>>>(hp.xsrc, rowptr + (size_t)h * N, eidx, meanb, N);
        if (hp.mode == 0)
            sage_gemm_mfma<0><<<gemmBlocks, 256, 0, stream>>>(meanb, hp.xdst, hp.W, hp.bl,
                                                              hib, nullptr, nullptr, nullptr, N);
        else if (hp.mode == 1)
            sage_gemm_mfma<1><<<gemmBlocks, 256, 0, stream>>>(meanb, hp.xdst, hp.W, hp.bl,
                                                              nullptr, hp.v, vbuf + 2 * DIM, out, N);
        else
            sage_gemm_mfma<2><<<gemmBlocks, 256, 0, stream>>>(meanb, hp.xdst, hp.W, hp.bl,
                                                              nullptr, hp.v, vbuf + 2 * DIM, out, N);
    }
}

// Round 6
// 535.728 us; speedup vs baseline: 6.1811x; 1.3370x over previous
//
#include <hip/hip_runtime.h>

#define DIM 128
#define CHUNK 8192
typedef unsigned short ushort_t;
typedef short bf16x8 __attribute__((ext_vector_type(8)));
typedef float f32x4 __attribute__((ext_vector_type(4)));

__device__ inline ushort_t f2bf(float f) {
    unsigned int u = __float_as_uint(f);
    unsigned int r = (u + 0x7FFFu + ((u >> 16) & 1u)) >> 16;
    return (ushort_t)r;
}
__device__ inline unsigned int pack2bf(float lo, float hi) {
    return (unsigned int)f2bf(lo) | ((unsigned int)f2bf(hi) << 16);
}
__device__ inline float bflo2f(unsigned int u) { return __uint_as_float(u << 16); }
__device__ inline float bfhi2f(unsigned int u) { return __uint_as_float(u & 0xFFFF0000u); }

// ---------------------------------------------------------------------------
__global__ void f32_to_bf16_kernel(const float* __restrict__ in, ushort_t* __restrict__ out, int n4) {
    int i = blockIdx.x * blockDim.x + threadIdx.x;
    int stride = gridDim.x * blockDim.x;
    for (; i < n4; i += stride) {
        float4 v = *reinterpret_cast<const float4*>(in + (size_t)i * 4);
        ushort_t o[4] = {f2bf(v.x), f2bf(v.y), f2bf(v.z), f2bf(v.w)};
        *reinterpret_cast<uint2*>(out + (size_t)i * 4) = *reinterpret_cast<uint2*>(o);
    }
}

__global__ void pack_weights_kernel(const float* __restrict__ Wl, const float* __restrict__ Wr,
                                    ushort_t* __restrict__ Wcat) {
    int j = blockIdx.x, k = threadIdx.x;
    float v = (k < DIM) ? Wl[j * DIM + k] : Wr[j * DIM + (k - DIM)];
    Wcat[j * 256 + k] = f2bf(v);
}

// ---------------------------------------------------------------------------
__global__ void precompute_v_kernel(const float* __restrict__ outW0,
                                    const float* __restrict__ outW1,
                                    const float* __restrict__ outb0,
                                    const float* __restrict__ outb1,
                                    const float* __restrict__ regW,
                                    const float* __restrict__ regb,
                                    float* __restrict__ vbuf) {
    int t = threadIdx.x;
    if (t < DIM) {
        float s = 0.f;
        #pragma unroll 8
        for (int j = 0; j < DIM; ++j) s = fmaf(outW0[j * DIM + t], regW[j], s);
        vbuf[t] = s;
    } else {
        int k = t - DIM;
        float s = 0.f;
        #pragma unroll 8
        for (int j = 0; j < DIM; ++j) s = fmaf(outW1[j * DIM + k], regW[DIM + j], s);
        vbuf[t] = s;
    }
    if (t == 0) {
        float c = regb[0];
        for (int j = 0; j < DIM; ++j) c += outb0[j] * regW[j] + outb1[j] * regW[DIM + j];
        vbuf[2 * DIM] = c;
    }
}

// ---------------------------------------------------------------------------
// Batched CSR build over 4 edge lists.
// ---------------------------------------------------------------------------
struct EdgePtrs { const int* e[4]; };

__global__ void hist4_kernel(EdgePtrs eps, int nedges, int* __restrict__ deg, int N) {
    int list = blockIdx.y;
    const int* __restrict__ dst = eps.e[list] + nedges;
    int* __restrict__ d = deg + (size_t)list * N;
    int i = blockIdx.x * blockDim.x + threadIdx.x;
    int stride = gridDim.x * blockDim.x;
    for (int e = i; e < nedges; e += stride) atomicAdd(&d[dst[e]], 1);
}

__global__ void scan_reduce_kernel(const int* __restrict__ deg, int* __restrict__ bsum, int n) {
    int i = blockIdx.x * 512 + threadIdx.x;
    int v = (i < n) ? deg[i] : 0;
    #pragma unroll
    for (int off = 32; off >= 1; off >>= 1) v += __shfl_down(v, off);
    __shared__ int wsum[8];
    int lane = threadIdx.x & 63, w = threadIdx.x >> 6;
    if (lane == 0) wsum[w] = v;
    __syncthreads();
    if (threadIdx.x == 0) {
        int s = 0;
        #pragma unroll
        for (int k = 0; k < 8; ++k) s += wsum[k];
        bsum[blockIdx.x] = s;
    }
}

__global__ void scan_blocksums_kernel(int* __restrict__ bsum, int nb) {
    __shared__ int s[1024];
    int t = threadIdx.x;
    s[t] = (t < nb) ? bsum[t] : 0;
    __syncthreads();
    for (int off = 1; off < 1024; off <<= 1) {
        int v = (t >= off) ? s[t - off] : 0;
        __syncthreads();
        s[t] += v;
        __syncthreads();
    }
    if (t < nb) bsum[t] = (t == 0) ? 0 : s[t - 1];
}

__global__ void scan_write_kernel(const int* __restrict__ deg, const int* __restrict__ bsum,
                                  int* __restrict__ rowptr, int* __restrict__ cursor,
                                  int n, int total) {
    int i = blockIdx.x * 512 + threadIdx.x;
    int v = (i < n) ? deg[i] : 0;
    int lane = threadIdx.x & 63, w = threadIdx.x >> 6;
    int sv = v;
    #pragma unroll
    for (int off = 1; off < 64; off <<= 1) {
        int u = __shfl_up(sv, off);
        if (lane >= off) sv += u;
    }
    __shared__ int wsum[8];
    if (lane == 63) wsum[w] = sv;
    __syncthreads();
    int base = bsum[blockIdx.x];
    #pragma unroll
    for (int k = 0; k < 8; ++k)
        if (k < w) base += wsum[k];
    int ex = base + sv - v;
    if (i < n) {
        rowptr[i] = ex;
        cursor[i] = ex;
    }
    if (blockIdx.x == 0 && threadIdx.x == 0) rowptr[n] = total;
}

// bcur[l*nbuck+b] = rowptr[l*N + min(b*256, N)]
__global__ void init_bcur_kernel(const int* __restrict__ rowptr, int* __restrict__ bcur,
                                 int N, int nbuck) {
    int i = blockIdx.x * blockDim.x + threadIdx.x;
    if (i < 4 * nbuck) {
        int l = i / nbuck, b = i - l * nbuck;
        int d = b << 8;
        if (d > N) d = N;
        bcur[i] = rowptr[(size_t)l * N + d];
    }
}

// Pass A: bin edges by bucket (dst>>8) into bucket-contiguous (src,dst) pairs.
// Per-workgroup LDS histogram + one global reserve per bucket -> bursts of
// ~CHUNK/nbuck pairs written by a single workgroup (single XCD) => low write amp.
__global__ void bin4_kernel(EdgePtrs eps, int nedges, int* __restrict__ bcur,
                            uint2* __restrict__ pairs, int nbuck) {
    int list = blockIdx.y;
    const int* __restrict__ src = eps.e[list];
    const int* __restrict__ dst = eps.e[list] + nedges;
    __shared__ int cnt[512], goff[512];
    const int tid = threadIdx.x;
    const int base = blockIdx.x * CHUNK;
    for (int b = tid; b < nbuck; b += 256) cnt[b] = 0;
    __syncthreads();
    int dstv[CHUNK / 256];
    #pragma unroll
    for (int it = 0; it < CHUNK / 256; ++it) {
        int e = base + it * 256 + tid;
        int d = (e < nedges) ? dst[e] : -1;
        dstv[it] = d;
        if (d >= 0) atomicAdd(&cnt[d >> 8], 1);
    }
    __syncthreads();
    for (int b = tid; b < nbuck; b += 256) {
        int c = cnt[b];
        goff[b] = (c > 0) ? atomicAdd(&bcur[list * nbuck + b], c) : 0;
        cnt[b] = 0;   // reuse as local rank counter
    }
    __syncthreads();
    #pragma unroll
    for (int it = 0; it < CHUNK / 256; ++it) {
        int d = dstv[it];
        if (d >= 0) {
            int e = base + it * 256 + tid;
            int b = d >> 8;
            int r = atomicAdd(&cnt[b], 1);
            pairs[goff[b] + r] = make_uint2((unsigned int)src[e], (unsigned int)d);
        }
    }
}

// Pass B: exact per-dst placement within each bucket region. One workgroup per
// (bucket, list): all eidx writes land in that workgroup's private ~8KB region.
__global__ void fillb_kernel(const uint2* __restrict__ pairs, const int* __restrict__ rowptr,
                             int* __restrict__ cursor, int* __restrict__ eidx,
                             int N, int nbuck) {
    int list = blockIdx.y;
    int b = blockIdx.x;
    int d0 = b << 8;
    int d1 = d0 + 256; if (d1 > N) d1 = N;
    if (d0 >= N) return;
    int beg = rowptr[(size_t)list * N + d0];
    int end = rowptr[(size_t)list * N + d1];
    for (int i = beg + (int)threadIdx.x; i < end; i += (int)blockDim.x) {
        uint2 p = pairs[i];
        int pos = atomicAdd(&cursor[(size_t)list * N + (int)p.y], 1);
        eidx[pos] = (int)p.x;
    }
}

// ---------------------------------------------------------------------------
// Gather-side mean, 4-edge MLP: one wave per row; sub-group s (16 lanes, uint4
// = 16B = 8 bf16 per lane) handles edges j = beg + it*4 + s.
// ---------------------------------------------------------------------------
__global__ void aggregate_kernel(const ushort_t* __restrict__ xsrc,
                                 const int* __restrict__ rowptr,
                                 const int* __restrict__ eidx,
                                 ushort_t* __restrict__ mean, int n) {
    int wid = (blockIdx.x * blockDim.x + threadIdx.x) >> 6;
    int lane = threadIdx.x & 63;
    int nw = (gridDim.x * blockDim.x) >> 6;
    const int sub = lane >> 4;
    const int lr = lane & 15;
    for (int r = wid; r < n; r += nw) {
        int beg = rowptr[r];
        int end = rowptr[r + 1];
        int deg = end - beg;
        float a[8] = {0.f, 0.f, 0.f, 0.f, 0.f, 0.f, 0.f, 0.f};
        int nit = (deg + 3) >> 2;
        for (int it = 0; it < nit; ++it) {
            int j = beg + it * 4 + sub;
            if (j < end) {
                int s = eidx[j];
                uint4 u = *reinterpret_cast<const uint4*>(xsrc + (size_t)s * DIM + lr * 8);
                a[0] += bflo2f(u.x); a[1] += bfhi2f(u.x);
                a[2] += bflo2f(u.y); a[3] += bfhi2f(u.y);
                a[4] += bflo2f(u.z); a[5] += bfhi2f(u.z);
                a[6] += bflo2f(u.w); a[7] += bfhi2f(u.w);
            }
        }
        #pragma unroll
        for (int k = 0; k < 8; ++k) {
            a[k] += __shfl_xor(a[k], 16);
            a[k] += __shfl_xor(a[k], 32);
        }
        if (sub == 0) {
            float sc = 1.0f / fmaxf((float)deg, 1.0f);
            uint4 o;
            o.x = pack2bf(a[0] * sc, a[1] * sc);
            o.y = pack2bf(a[2] * sc, a[3] * sc);
            o.z = pack2bf(a[4] * sc, a[5] * sc);
            o.w = pack2bf(a[6] * sc, a[7] * sc);
            *reinterpret_cast<uint4*>(mean + (size_t)r * DIM + lr * 8) = o;
        }
    }
}

// ---------------------------------------------------------------------------
// MFMA SAGE hop GEMM (bf16 in, f32 accum).
// ---------------------------------------------------------------------------
template <int MODE>
__launch_bounds__(256, 2)
__global__ void sage_gemm_mfma(const ushort_t* __restrict__ A0,
                               const ushort_t* __restrict__ A1,
                               const ushort_t* __restrict__ Wcat,
                               const float* __restrict__ bl,
                               ushort_t* __restrict__ H,
                               const float* __restrict__ v,
                               const float* __restrict__ cptr,
                               float* __restrict__ out,
                               int nrows) {
    __shared__ ushort_t As[128][40];
    __shared__ ushort_t Bs[128][40];
    __shared__ float red[2][128];

    const int tid = threadIdx.x;
    const int lane = tid & 63;
    const int w = tid >> 6;
    const int wr = w >> 1, wc = w & 1;
    const int lr = lane & 15;
    const int lk = (lane >> 4) * 8;
    const int row0 = blockIdx.x * 128;

    f32x4 acc[4][4];
    #pragma unroll
    for (int m = 0; m < 4; ++m)
        #pragma unroll
        for (int n = 0; n < 4; ++n)
            acc[m][n] = (f32x4){0.f, 0.f, 0.f, 0.f};

    for (int kt = 0; kt < 8; ++kt) {
        const int kb = kt * 32;
        const ushort_t* __restrict__ Asrc = (kb < DIM) ? A0 : A1;
        const int kbb = kb & (DIM - 1);

        #pragma unroll
        for (int p = 0; p < 2; ++p) {
            int idx = p * 256 + tid;
            int r = idx >> 2, c = idx & 3;
            int grow = row0 + r;
            uint4 val = make_uint4(0u, 0u, 0u, 0u);
            if (grow < nrows)
                val = *reinterpret_cast<const uint4*>(Asrc + (size_t)grow * DIM + kbb + c * 8);
            *reinterpret_cast<uint4*>(&As[r][c * 8]) = val;
        }
        #pragma unroll
        for (int p = 0; p < 2; ++p) {
            int idx = p * 256 + tid;
            int j = idx >> 2, c = idx & 3;
            uint4 val = *reinterpret_cast<const uint4*>(Wcat + j * 256 + kb + c * 8);
            *reinterpret_cast<uint4*>(&Bs[j][c * 8]) = val;
        }
        __syncthreads();

        bf16x8 af[4], bfm[4];
        #pragma unroll
        for (int m = 0; m < 4; ++m)
            af[m] = *reinterpret_cast<const bf16x8*>(&As[wr * 64 + m * 16 + lr][lk]);
        #pragma unroll
        for (int n = 0; n < 4; ++n)
            bfm[n] = *reinterpret_cast<const bf16x8*>(&Bs[wc * 64 + n * 16 + lr][lk]);
        #pragma unroll
        for (int m = 0; m < 4; ++m)
            #pragma unroll
            for (int n = 0; n < 4; ++n)
                acc[m][n] = __builtin_amdgcn_mfma_f32_16x16x32_bf16(af[m], bfm[n], acc[m][n], 0, 0, 0);
        __syncthreads();
    }

    if (MODE == 0) {
        float blc[4];
        #pragma unroll
        for (int n = 0; n < 4; ++n) blc[n] = bl[wc * 64 + n * 16 + lr];
        #pragma unroll
        for (int m = 0; m < 4; ++m) {
            #pragma unroll
            for (int reg = 0; reg < 4; ++reg) {
                int row = row0 + wr * 64 + m * 16 + (lane >> 4) * 4 + reg;
                if (row < nrows) {
                    #pragma unroll
                    for (int n = 0; n < 4; ++n) {
                        int col = wc * 64 + n * 16 + lr;
                        H[(size_t)row * DIM + col] = f2bf(fmaxf(acc[m][n][reg] + blc[n], 0.f));
                    }
                }
            }
        }
    } else {
        float blc[4], vc[4];
        #pragma unroll
        for (int n = 0; n < 4; ++n) {
            int col = wc * 64 + n * 16 + lr;
            blc[n] = bl[col];
            vc[n] = v[col];
        }
        #pragma unroll
        for (int m = 0; m < 4; ++m) {
            float rp[4] = {0.f, 0.f, 0.f, 0.f};
            #pragma unroll
            for (int n = 0; n < 4; ++n)
                #pragma unroll
                for (int reg = 0; reg < 4; ++reg)
                    rp[reg] = fmaf(fmaxf(acc[m][n][reg] + blc[n], 0.f), vc[n], rp[reg]);
            #pragma unroll
            for (int reg = 0; reg < 4; ++reg) {
                float p = rp[reg];
                p += __shfl_xor(p, 1);
                p += __shfl_xor(p, 2);
                p += __shfl_xor(p, 4);
                p += __shfl_xor(p, 8);
                if (lr == 0)
                    red[wc][wr * 64 + m * 16 + (lane >> 4) * 4 + reg] = p;
            }
        }
        __syncthreads();
        if (tid < 128) {
            int row = row0 + tid;
            if (row < nrows) {
                float s = red[0][tid] + red[1][tid];
                if (MODE == 1) out[row] = cptr[0] + s;
                else out[row] += s;
            }
        }
    }
}

// ---------------------------------------------------------------------------
extern "C" void kernel_launch(void* const* d_in, const int* in_sizes, int n_in,
                              void* d_out, int out_size, void* d_ws, size_t ws_size,
                              hipStream_t stream) {
    const float* x_user = (const float*)d_in[0];
    const float* x_item = (const float*)d_in[1];
    const int* ei_m0_h0 = (const int*)d_in[2];
    const int* ei_m0_h1 = (const int*)d_in[3];
    const int* ei_m1_h0 = (const int*)d_in[4];
    const int* ei_m1_h1 = (const int*)d_in[5];
    const float* Wl00 = (const float*)d_in[6];
    const float* Wr00 = (const float*)d_in[7];
    const float* Wl01 = (const float*)d_in[8];
    const float* Wr01 = (const float*)d_in[9];
    const float* Wl10 = (const float*)d_in[10];
    const float* Wr10 = (const float*)d_in[11];
    const float* Wl11 = (const float*)d_in[12];
    const float* Wr11 = (const float*)d_in[13];
    const float* outW0 = (const float*)d_in[14];
    const float* outW1 = (const float*)d_in[15];
    const float* bl00 = (const float*)d_in[16];
    const float* bl01 = (const float*)d_in[17];
    const float* bl10 = (const float*)d_in[18];
    const float* bl11 = (const float*)d_in[19];
    const float* outb0 = (const float*)d_in[20];
    const float* outb1 = (const float*)d_in[21];
    const float* regW = (const float*)d_in[22];
    const float* regb = (const float*)d_in[23];

    const int N = in_sizes[0] / DIM;
    const int E = in_sizes[2] / 2;
    float* out = (float*)d_out;

    // ws: xbu | xbi | meanb | hib (bf16 N*128 each) | Wcat | vbuf |
    //     deg[4N] | rowptr[4N+1] | cursor[4N] | bsum | bcur[4*nbuck] | eidx[4E]
    // pairs[4E] (uint2, 25.6MB) ALIASES hib (25.6MB): pairs dies at fillb,
    // hib is first written by hop0's GEMM (stream-ordered, safe).
    const int n4 = 4 * N;
    const int nb = (n4 + 511) / 512;
    const int nbuck = (N + 255) >> 8;
    ushort_t* xbu = (ushort_t*)d_ws;
    ushort_t* xbi = xbu + (size_t)N * DIM;
    ushort_t* meanb = xbi + (size_t)N * DIM;
    ushort_t* hib = meanb + (size_t)N * DIM;
    uint2* pairs = (uint2*)hib;
    ushort_t* Wcat = hib + (size_t)N * DIM;
    float* vbuf = (float*)(Wcat + 4 * 128 * 256);
    int* deg = (int*)(vbuf + 2 * DIM + 1);
    int* rowptr = deg + n4;
    int* cursor = rowptr + n4 + 1;
    int* bsum = cursor + n4;
    int* bcur = bsum + nb;
    int* eidx = bcur + 4 * nbuck;

    // one-time conversions
    f32_to_bf16_kernel<<<2048, 256, 0, stream>>>(x_user, xbu, N * DIM / 4);
    f32_to_bf16_kernel<<<2048, 256, 0, stream>>>(x_item, xbi, N * DIM / 4);
    pack_weights_kernel<<<128, 256, 0, stream>>>(Wl00, Wr00, Wcat);
    pack_weights_kernel<<<128, 256, 0, stream>>>(Wl01, Wr01, Wcat + 1 * 32768);
    pack_weights_kernel<<<128, 256, 0, stream>>>(Wl10, Wr10, Wcat + 2 * 32768);
    pack_weights_kernel<<<128, 256, 0, stream>>>(Wl11, Wr11, Wcat + 3 * 32768);
    precompute_v_kernel<<<1, 256, 0, stream>>>(outW0, outW1, outb0, outb1, regW, regb, vbuf);

    // batched CSR build for all 4 edge lists
    EdgePtrs eps;
    eps.e[0] = ei_m0_h0; eps.e[1] = ei_m0_h1; eps.e[2] = ei_m1_h0; eps.e[3] = ei_m1_h1;
    hipMemsetAsync(deg, 0, (size_t)n4 * sizeof(int), stream);
    hist4_kernel<<<dim3(512, 4), 256, 0, stream>>>(eps, E, deg, N);
    scan_reduce_kernel<<<nb, 512, 0, stream>>>(deg, bsum, n4);
    scan_blocksums_kernel<<<1, 1024, 0, stream>>>(bsum, nb);
    scan_write_kernel<<<nb, 512, 0, stream>>>(deg, bsum, rowptr, cursor, n4, 4 * E);
    init_bcur_kernel<<<(4 * nbuck + 255) / 256, 256, 0, stream>>>(rowptr, bcur, N, nbuck);
    bin4_kernel<<<dim3((E + CHUNK - 1) / CHUNK, 4), 256, 0, stream>>>(eps, E, bcur, pairs, nbuck);
    fillb_kernel<<<dim3(nbuck, 4), 256, 0, stream>>>(pairs, rowptr, cursor, eidx, N, nbuck);

    const int gemmBlocks = (N + 127) / 128;
    const int aggBlocks = 2048;

    struct Hop {
        const ushort_t* xsrc;
        const ushort_t* xdst;
        const ushort_t* W;
        const float* bl;
        int mode;
        const float* v;
    };
    const Hop hops[4] = {
        {xbu, xbi, Wcat + 0 * 32768, bl00, 0, nullptr},
        {hib, xbu, Wcat + 1 * 32768, bl01, 1, vbuf},
        {xbu, xbi, Wcat + 2 * 32768, bl10, 0, nullptr},
        {hib, xbu, Wcat + 3 * 32768, bl11, 2, vbuf + DIM},
    };

    for (int h = 0; h < 4; ++h) {
        const Hop& hp = hops[h];
        aggregate_kernel<<<aggBlocks, 256, 0, stream>>>(hp.xsrc, rowptr + (size_t)h * N, eidx, meanb, N);
        if (hp.mode == 0)
            sage_gemm_mfma<0><<<gemmBlocks, 256, 0, stream>>>(meanb, hp.xdst, hp.W, hp.bl,
                                                              hib, nullptr, nullptr, nullptr, N);
        else if (hp.mode == 1)
            sage_gemm_mfma<1><<<gemmBlocks, 256, 0, stream>>>(meanb, hp.xdst, hp.W, hp.bl,
                                                              nullptr, hp.v, vbuf + 2 * DIM, out, N);
        else
            sage_gemm_mfma<2><<<gemmBlocks, 256, 0, stream>>>(meanb, hp.xdst, hp.W, hp.bl,
                                                              nullptr, hp.v, vbuf + 2 * DIM, out, N);
    }
}

// Round 7
// 391.819 us; speedup vs baseline: 8.4514x; 1.3673x over previous
//
#include <hip/hip_runtime.h>

#define DIM 128
#define CHUNK 8192
#define PAIRC 4080   // per-bucket pair slot capacity (mean 2046, +45 sigma)
typedef unsigned short ushort_t;
typedef short bf16x8 __attribute__((ext_vector_type(8)));
typedef float f32x4 __attribute__((ext_vector_type(4)));

__device__ inline ushort_t f2bf(float f) {
    unsigned int u = __float_as_uint(f);
    unsigned int r = (u + 0x7FFFu + ((u >> 16) & 1u)) >> 16;
    return (ushort_t)r;
}
__device__ inline unsigned int pack2bf(float lo, float hi) {
    return (unsigned int)f2bf(lo) | ((unsigned int)f2bf(hi) << 16);
}
__device__ inline float bflo2f(unsigned int u) { return __uint_as_float(u << 16); }
__device__ inline float bfhi2f(unsigned int u) { return __uint_as_float(u & 0xFFFF0000u); }

// ---------------------------------------------------------------------------
__global__ void f32_to_bf16_kernel(const float* __restrict__ in, ushort_t* __restrict__ out, int n4) {
    int i = blockIdx.x * blockDim.x + threadIdx.x;
    int stride = gridDim.x * blockDim.x;
    for (; i < n4; i += stride) {
        float4 v = *reinterpret_cast<const float4*>(in + (size_t)i * 4);
        ushort_t o[4] = {f2bf(v.x), f2bf(v.y), f2bf(v.z), f2bf(v.w)};
        *reinterpret_cast<uint2*>(out + (size_t)i * 4) = *reinterpret_cast<uint2*>(o);
    }
}

__global__ void pack_weights_kernel(const float* __restrict__ Wl, const float* __restrict__ Wr,
                                    ushort_t* __restrict__ Wcat) {
    int j = blockIdx.x, k = threadIdx.x;
    float v = (k < DIM) ? Wl[j * DIM + k] : Wr[j * DIM + (k - DIM)];
    Wcat[j * 256 + k] = f2bf(v);
}

// ---------------------------------------------------------------------------
__global__ void precompute_v_kernel(const float* __restrict__ outW0,
                                    const float* __restrict__ outW1,
                                    const float* __restrict__ outb0,
                                    const float* __restrict__ outb1,
                                    const float* __restrict__ regW,
                                    const float* __restrict__ regb,
                                    float* __restrict__ vbuf) {
    int t = threadIdx.x;
    if (t < DIM) {
        float s = 0.f;
        #pragma unroll 8
        for (int j = 0; j < DIM; ++j) s = fmaf(outW0[j * DIM + t], regW[j], s);
        vbuf[t] = s;
    } else {
        int k = t - DIM;
        float s = 0.f;
        #pragma unroll 8
        for (int j = 0; j < DIM; ++j) s = fmaf(outW1[j * DIM + k], regW[DIM + j], s);
        vbuf[t] = s;
    }
    if (t == 0) {
        float c = regb[0];
        for (int j = 0; j < DIM; ++j) c += outb0[j] * regW[j] + outb1[j] * regW[DIM + j];
        vbuf[2 * DIM] = c;
    }
}

// ---------------------------------------------------------------------------
// CSR build without a global histogram:
//   bin4_direct: LDS bucket-count per chunk, reserve bursts in fixed-capacity
//     per-(list,bucket) pair slots via tiny bcnt cursors; bcnt ends as counts.
//   bucket_scan: exclusive scan of the 4*nbuck counts -> global eidx bases.
//   fillb: per-bucket LDS dst-histogram + LDS scan -> rowptr + exact eidx
//     placement with LDS cursors (no dst-granular global atomics anywhere).
// ---------------------------------------------------------------------------
struct EdgePtrs { const int* e[4]; };

__global__ void bin4_direct_kernel(EdgePtrs eps, int nedges, int* __restrict__ bcnt,
                                   uint2* __restrict__ pairs, int nbuck) {
    int list = blockIdx.y;
    const int* __restrict__ src = eps.e[list];
    const int* __restrict__ dst = eps.e[list] + nedges;
    __shared__ int cnt[512], goff[512];
    const int tid = threadIdx.x;
    const int base = blockIdx.x * CHUNK;
    for (int b = tid; b < nbuck; b += 256) cnt[b] = 0;
    __syncthreads();
    int dstv[CHUNK / 256];
    #pragma unroll
    for (int it = 0; it < CHUNK / 256; ++it) {
        int e = base + it * 256 + tid;
        int d = (e < nedges) ? dst[e] : -1;
        dstv[it] = d;
        if (d >= 0) atomicAdd(&cnt[d >> 8], 1);
    }
    __syncthreads();
    for (int b = tid; b < nbuck; b += 256) {
        int c = cnt[b];
        goff[b] = (c > 0) ? atomicAdd(&bcnt[list * nbuck + b], c) : 0;
        cnt[b] = 0;   // reuse as local rank counter
    }
    __syncthreads();
    #pragma unroll
    for (int it = 0; it < CHUNK / 256; ++it) {
        int d = dstv[it];
        if (d >= 0) {
            int e = base + it * 256 + tid;
            int b = d >> 8;
            int r = atomicAdd(&cnt[b], 1);
            pairs[((size_t)list * nbuck + b) * PAIRC + goff[b] + r] =
                make_uint2((unsigned int)src[e], (unsigned int)d);
        }
    }
}

// single block, 512 threads, 4 elems/thread; n = 4*nbuck <= 2048
__global__ void bucket_scan_kernel(const int* __restrict__ bcnt, int* __restrict__ bbase,
                                   int n, int* __restrict__ rowptr, int n4, int total) {
    int t = threadIdx.x;
    int loc[4];
    int s = 0;
    #pragma unroll
    for (int k = 0; k < 4; ++k) {
        int i = t * 4 + k;
        loc[k] = (i < n) ? bcnt[i] : 0;
        s += loc[k];
    }
    int lane = t & 63, w = t >> 6;
    int sv = s;
    #pragma unroll
    for (int off = 1; off < 64; off <<= 1) {
        int u = __shfl_up(sv, off);
        if (lane >= off) sv += u;
    }
    __shared__ int wsum[8];
    if (lane == 63) wsum[w] = sv;
    __syncthreads();
    int base = 0;
    #pragma unroll
    for (int k = 0; k < 8; ++k)
        if (k < w) base += wsum[k];
    int ex = base + sv - s;
    #pragma unroll
    for (int k = 0; k < 4; ++k) {
        int i = t * 4 + k;
        if (i < n) bbase[i] = ex;
        ex += loc[k];
    }
    if (t == 0) rowptr[n4] = total;
}

// one block per (bucket, list): LDS histogram over 256 local dst, LDS scan,
// coalesced rowptr write, LDS-cursor placement into private eidx region.
__global__ void fillb_kernel(const uint2* __restrict__ pairs, const int* __restrict__ bcnt,
                             const int* __restrict__ bbase, int* __restrict__ rowptr,
                             int* __restrict__ eidx, int N, int nbuck) {
    int list = blockIdx.y;
    int b = blockIdx.x;
    int d0 = b << 8;
    if (d0 >= N) return;
    int nd = N - d0; if (nd > 256) nd = 256;
    int slot = list * nbuck + b;
    int cnt = bcnt[slot];
    int base = bbase[slot];
    const uint2* __restrict__ ps = pairs + (size_t)slot * PAIRC;

    __shared__ int h[256], cur[256];
    int t = threadIdx.x;   // 256 threads
    h[t] = 0;
    __syncthreads();
    for (int i = t; i < cnt; i += 256) atomicAdd(&h[ps[i].y & 255], 1);
    __syncthreads();
    // exclusive scan of h[0..256) across 4 waves
    int v = h[t];
    int lane = t & 63, w = t >> 6;
    int sv = v;
    #pragma unroll
    for (int off = 1; off < 64; off <<= 1) {
        int u = __shfl_up(sv, off);
        if (lane >= off) sv += u;
    }
    __shared__ int wsum[4];
    if (lane == 63) wsum[w] = sv;
    __syncthreads();
    int wbase = 0;
    #pragma unroll
    for (int k = 0; k < 4; ++k)
        if (k < w) wbase += wsum[k];
    int ex = wbase + sv - v;
    if (t < nd) rowptr[(size_t)list * N + d0 + t] = base + ex;
    cur[t] = ex;
    __syncthreads();
    for (int i = t; i < cnt; i += 256) {
        uint2 p = ps[i];
        int ld = (int)(p.y & 255u);
        int r = atomicAdd(&cur[ld], 1);
        eidx[base + r] = (int)p.x;
    }
}

// ---------------------------------------------------------------------------
// Gather-side mean, 4-edge MLP: one wave per row; sub-group s (16 lanes, uint4
// = 16B = 8 bf16 per lane) handles edges j = beg + it*4 + s.
// ---------------------------------------------------------------------------
__global__ void aggregate_kernel(const ushort_t* __restrict__ xsrc,
                                 const int* __restrict__ rowptr,
                                 const int* __restrict__ eidx,
                                 ushort_t* __restrict__ mean, int n) {
    int wid = (blockIdx.x * blockDim.x + threadIdx.x) >> 6;
    int lane = threadIdx.x & 63;
    int nw = (gridDim.x * blockDim.x) >> 6;
    const int sub = lane >> 4;
    const int lr = lane & 15;
    for (int r = wid; r < n; r += nw) {
        int beg = rowptr[r];
        int end = rowptr[r + 1];
        int deg = end - beg;
        float a[8] = {0.f, 0.f, 0.f, 0.f, 0.f, 0.f, 0.f, 0.f};
        int nit = (deg + 3) >> 2;
        for (int it = 0; it < nit; ++it) {
            int j = beg + it * 4 + sub;
            if (j < end) {
                int s = eidx[j];
                uint4 u = *reinterpret_cast<const uint4*>(xsrc + (size_t)s * DIM + lr * 8);
                a[0] += bflo2f(u.x); a[1] += bfhi2f(u.x);
                a[2] += bflo2f(u.y); a[3] += bfhi2f(u.y);
                a[4] += bflo2f(u.z); a[5] += bfhi2f(u.z);
                a[6] += bflo2f(u.w); a[7] += bfhi2f(u.w);
            }
        }
        #pragma unroll
        for (int k = 0; k < 8; ++k) {
            a[k] += __shfl_xor(a[k], 16);
            a[k] += __shfl_xor(a[k], 32);
        }
        if (sub == 0) {
            float sc = 1.0f / fmaxf((float)deg, 1.0f);
            uint4 o;
            o.x = pack2bf(a[0] * sc, a[1] * sc);
            o.y = pack2bf(a[2] * sc, a[3] * sc);
            o.z = pack2bf(a[4] * sc, a[5] * sc);
            o.w = pack2bf(a[6] * sc, a[7] * sc);
            *reinterpret_cast<uint4*>(mean + (size_t)r * DIM + lr * 8) = o;
        }
    }
}

// ---------------------------------------------------------------------------
// MFMA SAGE hop GEMM (bf16 in, f32 accum).
// ---------------------------------------------------------------------------
template <int MODE>
__launch_bounds__(256, 2)
__global__ void sage_gemm_mfma(const ushort_t* __restrict__ A0,
                               const ushort_t* __restrict__ A1,
                               const ushort_t* __restrict__ Wcat,
                               const float* __restrict__ bl,
                               ushort_t* __restrict__ H,
                               const float* __restrict__ v,
                               const float* __restrict__ cptr,
                               float* __restrict__ out,
                               int nrows) {
    __shared__ ushort_t As[128][40];
    __shared__ ushort_t Bs[128][40];
    __shared__ float red[2][128];

    const int tid = threadIdx.x;
    const int lane = tid & 63;
    const int w = tid >> 6;
    const int wr = w >> 1, wc = w & 1;
    const int lr = lane & 15;
    const int lk = (lane >> 4) * 8;
    const int row0 = blockIdx.x * 128;

    f32x4 acc[4][4];
    #pragma unroll
    for (int m = 0; m < 4; ++m)
        #pragma unroll
        for (int n = 0; n < 4; ++n)
            acc[m][n] = (f32x4){0.f, 0.f, 0.f, 0.f};

    for (int kt = 0; kt < 8; ++kt) {
        const int kb = kt * 32;
        const ushort_t* __restrict__ Asrc = (kb < DIM) ? A0 : A1;
        const int kbb = kb & (DIM - 1);

        #pragma unroll
        for (int p = 0; p < 2; ++p) {
            int idx = p * 256 + tid;
            int r = idx >> 2, c = idx & 3;
            int grow = row0 + r;
            uint4 val = make_uint4(0u, 0u, 0u, 0u);
            if (grow < nrows)
                val = *reinterpret_cast<const uint4*>(Asrc + (size_t)grow * DIM + kbb + c * 8);
            *reinterpret_cast<uint4*>(&As[r][c * 8]) = val;
        }
        #pragma unroll
        for (int p = 0; p < 2; ++p) {
            int idx = p * 256 + tid;
            int j = idx >> 2, c = idx & 3;
            uint4 val = *reinterpret_cast<const uint4*>(Wcat + j * 256 + kb + c * 8);
            *reinterpret_cast<uint4*>(&Bs[j][c * 8]) = val;
        }
        __syncthreads();

        bf16x8 af[4], bfm[4];
        #pragma unroll
        for (int m = 0; m < 4; ++m)
            af[m] = *reinterpret_cast<const bf16x8*>(&As[wr * 64 + m * 16 + lr][lk]);
        #pragma unroll
        for (int n = 0; n < 4; ++n)
            bfm[n] = *reinterpret_cast<const bf16x8*>(&Bs[wc * 64 + n * 16 + lr][lk]);
        #pragma unroll
        for (int m = 0; m < 4; ++m)
            #pragma unroll
            for (int n = 0; n < 4; ++n)
                acc[m][n] = __builtin_amdgcn_mfma_f32_16x16x32_bf16(af[m], bfm[n], acc[m][n], 0, 0, 0);
        __syncthreads();
    }

    if (MODE == 0) {
        float blc[4];
        #pragma unroll
        for (int n = 0; n < 4; ++n) blc[n] = bl[wc * 64 + n * 16 + lr];
        #pragma unroll
        for (int m = 0; m < 4; ++m) {
            #pragma unroll
            for (int reg = 0; reg < 4; ++reg) {
                int row = row0 + wr * 64 + m * 16 + (lane >> 4) * 4 + reg;
                if (row < nrows) {
                    #pragma unroll
                    for (int n = 0; n < 4; ++n) {
                        int col = wc * 64 + n * 16 + lr;
                        H[(size_t)row * DIM + col] = f2bf(fmaxf(acc[m][n][reg] + blc[n], 0.f));
                    }
                }
            }
        }
    } else {
        float blc[4], vc[4];
        #pragma unroll
        for (int n = 0; n < 4; ++n) {
            int col = wc * 64 + n * 16 + lr;
            blc[n] = bl[col];
            vc[n] = v[col];
        }
        #pragma unroll
        for (int m = 0; m < 4; ++m) {
            float rp[4] = {0.f, 0.f, 0.f, 0.f};
            #pragma unroll
            for (int n = 0; n < 4; ++n)
                #pragma unroll
                for (int reg = 0; reg < 4; ++reg)
                    rp[reg] = fmaf(fmaxf(acc[m][n][reg] + blc[n], 0.f), vc[n], rp[reg]);
            #pragma unroll
            for (int reg = 0; reg < 4; ++reg) {
                float p = rp[reg];
                p += __shfl_xor(p, 1);
                p += __shfl_xor(p, 2);
                p += __shfl_xor(p, 4);
                p += __shfl_xor(p, 8);
                if (lr == 0)
                    red[wc][wr * 64 + m * 16 + (lane >> 4) * 4 + reg] = p;
            }
        }
        __syncthreads();
        if (tid < 128) {
            int row = row0 + tid;
            if (row < nrows) {
                float s = red[0][tid] + red[1][tid];
                if (MODE == 1) out[row] = cptr[0] + s;
                else out[row] += s;
            }
        }
    }
}

// ---------------------------------------------------------------------------
extern "C" void kernel_launch(void* const* d_in, const int* in_sizes, int n_in,
                              void* d_out, int out_size, void* d_ws, size_t ws_size,
                              hipStream_t stream) {
    const float* x_user = (const float*)d_in[0];
    const float* x_item = (const float*)d_in[1];
    const int* ei_m0_h0 = (const int*)d_in[2];
    const int* ei_m0_h1 = (const int*)d_in[3];
    const int* ei_m1_h0 = (const int*)d_in[4];
    const int* ei_m1_h1 = (const int*)d_in[5];
    const float* Wl00 = (const float*)d_in[6];
    const float* Wr00 = (const float*)d_in[7];
    const float* Wl01 = (const float*)d_in[8];
    const float* Wr01 = (const float*)d_in[9];
    const float* Wl10 = (const float*)d_in[10];
    const float* Wr10 = (const float*)d_in[11];
    const float* Wl11 = (const float*)d_in[12];
    const float* Wr11 = (const float*)d_in[13];
    const float* outW0 = (const float*)d_in[14];
    const float* outW1 = (const float*)d_in[15];
    const float* bl00 = (const float*)d_in[16];
    const float* bl01 = (const float*)d_in[17];
    const float* bl10 = (const float*)d_in[18];
    const float* bl11 = (const float*)d_in[19];
    const float* outb0 = (const float*)d_in[20];
    const float* outb1 = (const float*)d_in[21];
    const float* regW = (const float*)d_in[22];
    const float* regb = (const float*)d_in[23];

    const int N = in_sizes[0] / DIM;
    const int E = in_sizes[2] / 2;
    float* out = (float*)d_out;

    // ws: xbu | xbi | meanb | hib (bf16 N*128 each) | Wcat | vbuf |
    //     bcnt[4*nbuck] | bbase[4*nbuck] | rowptr[4N+1] | eidx[4E]
    // pairs (uint2, 4*nbuck*PAIRC = 51.05MB) ALIASES meanb+hib (51.2MB):
    // pairs die at fillb; meanb first written by hop0 aggregate (stream-ordered).
    const int n4 = 4 * N;
    const int nbuck = (N + 255) >> 8;
    ushort_t* xbu = (ushort_t*)d_ws;
    ushort_t* xbi = xbu + (size_t)N * DIM;
    ushort_t* meanb = xbi + (size_t)N * DIM;
    ushort_t* hib = meanb + (size_t)N * DIM;
    uint2* pairs = (uint2*)meanb;
    ushort_t* Wcat = hib + (size_t)N * DIM;
    float* vbuf = (float*)(Wcat + 4 * 128 * 256);
    int* bcnt = (int*)(vbuf + 2 * DIM + 1);
    int* bbase = bcnt + 4 * nbuck;
    int* rowptr = bbase + 4 * nbuck;
    int* eidx = rowptr + n4 + 1;

    // one-time conversions
    f32_to_bf16_kernel<<<2048, 256, 0, stream>>>(x_user, xbu, N * DIM / 4);
    f32_to_bf16_kernel<<<2048, 256, 0, stream>>>(x_item, xbi, N * DIM / 4);
    pack_weights_kernel<<<128, 256, 0, stream>>>(Wl00, Wr00, Wcat);
    pack_weights_kernel<<<128, 256, 0, stream>>>(Wl01, Wr01, Wcat + 1 * 32768);
    pack_weights_kernel<<<128, 256, 0, stream>>>(Wl10, Wr10, Wcat + 2 * 32768);
    pack_weights_kernel<<<128, 256, 0, stream>>>(Wl11, Wr11, Wcat + 3 * 32768);
    precompute_v_kernel<<<1, 256, 0, stream>>>(outW0, outW1, outb0, outb1, regW, regb, vbuf);

    // CSR build (no global histogram)
    EdgePtrs eps;
    eps.e[0] = ei_m0_h0; eps.e[1] = ei_m0_h1; eps.e[2] = ei_m1_h0; eps.e[3] = ei_m1_h1;
    hipMemsetAsync(bcnt, 0, (size_t)4 * nbuck * sizeof(int), stream);
    bin4_direct_kernel<<<dim3((E + CHUNK - 1) / CHUNK, 4), 256, 0, stream>>>(eps, E, bcnt, pairs, nbuck);
    bucket_scan_kernel<<<1, 512, 0, stream>>>(bcnt, bbase, 4 * nbuck, rowptr, n4, 4 * E);
    fillb_kernel<<<dim3(nbuck, 4), 256, 0, stream>>>(pairs, bcnt, bbase, rowptr, eidx, N, nbuck);

    const int gemmBlocks = (N + 127) / 128;
    const int aggBlocks = 2048;

    struct Hop {
        const ushort_t* xsrc;
        const ushort_t* xdst;
        const ushort_t* W;
        const float* bl;
        int mode;
        const float* v;
    };
    const Hop hops[4] = {
        {xbu, xbi, Wcat + 0 * 32768, bl00, 0, nullptr},
        {hib, xbu, Wcat + 1 * 32768, bl01, 1, vbuf},
        {xbu, xbi, Wcat + 2 * 32768, bl10, 0, nullptr},
        {hib, xbu, Wcat + 3 * 32768, bl11, 2, vbuf + DIM},
    };

    for (int h = 0; h < 4; ++h) {
        const Hop& hp = hops[h];
        aggregate_kernel<<<aggBlocks, 256, 0, stream>>>(hp.xsrc, rowptr + (size_t)h * N, eidx, meanb, N);
        if (hp.mode == 0)
            sage_gemm_mfma<0><<<gemmBlocks, 256, 0, stream>>>(meanb, hp.xdst, hp.W, hp.bl,
                                                              hib, nullptr, nullptr, nullptr, N);
        else if (hp.mode == 1)
            sage_gemm_mfma<1><<<gemmBlocks, 256, 0, stream>>>(meanb, hp.xdst, hp.W, hp.bl,
                                                              nullptr, hp.v, vbuf + 2 * DIM, out, N);
        else
            sage_gemm_mfma<2><<<gemmBlocks, 256, 0, stream>>>(meanb, hp.xdst, hp.W, hp.bl,
                                                              nullptr, hp.v, vbuf + 2 * DIM, out, N);
    }
}